// Round 5
// baseline (1112.732 us; speedup 1.0000x reference)
//
#include <hip/hip_runtime.h>
#include <hip/hip_bf16.h>

#define NN 16384
#define NC 64
#define GH 128
#define GW 128
#define GM 256

static __device__ __forceinline__ int reflect128(int i){
  if (i < 0) i = -i;
  if (i > 127) i = 254 - i;
  return i;
}

// px = round(0.5*(loc+1)*S - 0.5): (loc+1) rounds once; *S2 (pow2) exact;
// -0.5 rounds once == reference's f32 sequence bit-for-bit.
static __device__ __forceinline__ int cell_of(float l, float S2, int hi){
  l = fminf(fmaxf(l, -1.f), 1.f);
  float u = l + 1.f;
  int p = (int)rintf(u*S2 - 0.5f);
  return min(max(p,0),hi);
}

// scatter x_source into feature grid (thread per token*channel); local-batch
__global__ __launch_bounds__(256) void k_scatter_feat(
    const float* __restrict__ xsrc, const float* __restrict__ loc,
    float* __restrict__ featg){
  int gid = blockIdx.x*256 + threadIdx.x;
  int t = gid >> 6;
  int b = t >> 14;
  int px = cell_of(loc[2*t],   64.f, 127);
  int py = cell_of(loc[2*t+1], 64.f, 127);
  int cell = (b*GH + py)*GW + px;
  atomicAdd(&featg[cell*NC + (gid & 63)], xsrc[gid]);
}

// counts + conf scatter (thread per token)
__global__ __launch_bounds__(256) void k_scatter_aux(
    const float* __restrict__ loc, const float* __restrict__ csrc,
    float* __restrict__ cnt, float* __restrict__ csum, float* __restrict__ ccnt){
  int t = blockIdx.x*256 + threadIdx.x;
  int b = t >> 14;
  int px = cell_of(loc[2*t],   64.f, 127);
  int py = cell_of(loc[2*t+1], 64.f, 127);
  atomicAdd(&cnt[(b*GH+py)*GW+px], 1.0f);
  int qx = cell_of(loc[2*t],   8.f, 15);
  int qy = cell_of(loc[2*t+1], 8.f, 15);
  int cell = b*GM + qy*16 + qx;
  atomicAdd(&csum[cell], csrc[t]);
  atomicAdd(&ccnt[cell], 1.0f);
}

// featg := featg/(cnt+eps) * (cnt>0)   (in place)
__global__ __launch_bounds__(256) void k_finalize_feat(
    float* __restrict__ featg, const float* __restrict__ cnt){
  int gid = blockIdx.x*256 + threadIdx.x;
  float cn = cnt[gid>>6];
  float v  = featg[gid];
  featg[gid] = (cn > 0.f) ? v/(cn+1e-6f) : 0.f;
}

__global__ __launch_bounds__(256) void k_finalize_conf(
    const float* __restrict__ csum, const float* __restrict__ ccnt,
    float* __restrict__ conf){
  int i = blockIdx.x*256 + threadIdx.x;
  float cn = ccnt[i];
  conf[i] = (cn > 0.f) ? csum[i]/(cn+1e-6f) : 0.f;
}

// 9x9 gaussian hole fill, reflect pad; writes only cnt==0 pixels (no races:
// taps only read cnt>0 pixels which are never written here).
__global__ __launch_bounds__(256) void k_fill(
    const float* __restrict__ cnt, float* __restrict__ feat){
  int p = blockIdx.x*256 + threadIdx.x;
  if (cnt[p] > 0.f) return;
  int b = p>>14, py=(p>>7)&127, px=p&127;
  const float fn = 0.039788735772973836f;    // 1/(8*pi) == 1/(2*pi*var), var=4
  float g1[9];
  #pragma unroll
  for (int i=0;i<9;++i){ float d=(float)i-4.f; g1[i]=__expf(-d*d*0.125f); }
  float4 acc[16];
  #pragma unroll
  for (int i=0;i<16;++i) acc[i]=make_float4(0.f,0.f,0.f,0.f);
  float msum=0.f;
  for (int dy=0; dy<9; ++dy){
    int iy = reflect128(py-4+dy);
    for (int dx=0; dx<9; ++dx){
      int ix = reflect128(px-4+dx);
      int q  = (b*GH+iy)*GW+ix;
      if (cnt[q] <= 0.f) continue;           // mask==0 taps contribute nothing
      float wn = g1[dy]*g1[dx]*fn;
      msum += wn;
      const float4* fr = (const float4*)&feat[q*NC];
      #pragma unroll
      for (int k=0;k<16;++k){
        float4 vv = fr[k];
        acc[k].x += wn*vv.x; acc[k].y += wn*vv.y;
        acc[k].z += wn*vv.z; acc[k].w += wn*vv.w;
      }
    }
  }
  if (msum <= 0.f) return;
  float inv = 1.f/(msum + 1e-6f);
  float4* o = (float4*)&feat[p*NC];
  #pragma unroll
  for (int k=0;k<16;++k)
    o[k] = make_float4(acc[k].x*inv, acc[k].y*inv, acc[k].z*inv, acc[k].w*inv);
}

// NAIVE stride-8 8x8 conv: thread per (patch m, out-channel co).
__global__ __launch_bounds__(256) void k_srconv_naive(
    const float* __restrict__ feat, const float* __restrict__ srw,
    float* __restrict__ xs0){
  int gid = blockIdx.x*256 + threadIdx.x;
  int m = gid >> 6, co = gid & 63;
  int b = m>>8, oh=(m>>4)&15, ow=m&15;
  float acc = 0.f;
  for (int kh=0; kh<8; ++kh){
    for (int kw=0; kw<8; ++kw){
      const float* fp = &feat[((b*GH + oh*8+kh)*GW + ow*8+kw)*NC];
      const float* wp = &srw[((kh*8+kw)*64)*64 + co];
      for (int ci=0; ci<64; ++ci)
        acc += fp[ci]*wp[ci*64];
    }
  }
  xs0[gid] = acc;
}

// layernorm(xs0 + sr_b) -> xs   (wave per row)
__global__ __launch_bounds__(256) void k_ln(
    const float* __restrict__ xs0, const float* __restrict__ srb,
    const float* __restrict__ nw, const float* __restrict__ nbv,
    float* __restrict__ xs){
  int row  = blockIdx.x*4 + (threadIdx.x>>6);
  int lane = threadIdx.x & 63;
  float v = xs0[row*64+lane] + srb[lane];
  float s = v;
  #pragma unroll
  for (int off=32; off; off>>=1) s += __shfl_xor(s, off, 64);
  float mean = s*(1.f/64.f);
  float d = v - mean;
  float s2 = d*d;
  #pragma unroll
  for (int off=32; off; off>>=1) s2 += __shfl_xor(s2, off, 64);
  float var = s2*(1.f/64.f);
  xs[row*64+lane] = d*(1.f/sqrtf(var+1e-5f))*nw[lane] + nbv[lane];
}

// NAIVE kv: thread per (b,m,d): k and v projections.
__global__ __launch_bounds__(256) void k_kv1(
    const float* __restrict__ xs, const float* __restrict__ kvw,
    float* __restrict__ kT, float* __restrict__ vt){
  int gid = blockIdx.x*256 + threadIdx.x;
  int r = gid >> 6, d = gid & 63;              // r = b*256+m (local)
  int b = r >> 8, m = r & 255;
  const float* xr = &xs[r*64];
  float ka=0.f, va=0.f;
  for (int c=0;c<64;++c){
    float xc = xr[c];
    ka += xc*kvw[d*64+c];
    va += xc*kvw[(64+d)*64+c];
  }
  kT[(b*64+d)*GM + m] = ka;                    // [b][d][m]
  vt[gid] = va;                                // [b*256+m][d]
}

// NAIVE vp = v @ proj_w^T : thread per (b,m,co)
__global__ __launch_bounds__(256) void k_kv2(
    const float* __restrict__ vt, const float* __restrict__ projw,
    float* __restrict__ vp){
  int gid = blockIdx.x*256 + threadIdx.x;
  int r = gid >> 6, co = gid & 63;
  const float* vr = &vt[r*64];
  float acc = 0.f;
  for (int d=0; d<64; ++d)
    acc += vr[d]*projw[co*64+d];
  vp[gid] = acc;                               // [b*256+m][co]
}

// NAIVE fused q-proj + attention; one wave per query row.  f32 OUTPUT.
__global__ __launch_bounds__(256) void k_attn_naive(
    const float* __restrict__ x, const float* __restrict__ qw,
    const float* __restrict__ kT, const float* __restrict__ vp,
    const float* __restrict__ conf, const float* __restrict__ projb,
    float* __restrict__ out){
  __shared__ float QS[4][64];
  __shared__ float PS[4][256];
  int w = threadIdx.x>>6, lane = threadIdx.x&63;
  int row = blockIdx.x*4 + w;                  // local row
  int b = row >> 14;
  const float* xr = &x[(size_t)row*64];
  float qd = 0.f;
  for (int c=0;c<64;++c) qd += xr[c]*qw[lane*64+c];
  QS[w][lane] = qd;
  __syncthreads();
  float s[4];
  #pragma unroll
  for (int j=0;j<4;++j){
    int m = j*64 + lane;
    float acc = 0.f;
    for (int d=0;d<64;++d)
      acc += QS[w][d]*kT[(b*64+d)*GM + m];
    s[j] = acc*0.125f + conf[b*GM + m];
  }
  float mx = fmaxf(fmaxf(s[0],s[1]),fmaxf(s[2],s[3]));
  #pragma unroll
  for (int off=32; off; off>>=1) mx = fmaxf(mx, __shfl_xor(mx, off, 64));
  float e[4], sm = 0.f;
  #pragma unroll
  for (int j=0;j<4;++j){ e[j] = __expf(s[j]-mx); sm += e[j]; }
  #pragma unroll
  for (int off=32; off; off>>=1) sm += __shfl_xor(sm, off, 64);
  float inv = 1.f/sm;
  #pragma unroll
  for (int j=0;j<4;++j) PS[w][j*64+lane] = e[j]*inv;
  __syncthreads();
  float acc = 0.f;
  for (int m=0;m<256;++m)
    acc += PS[w][m]*vp[(b*GM+m)*64 + lane];
  out[(size_t)row*64+lane] = acc + projb[lane];
}

extern "C" void kernel_launch(void* const* d_in, const int* in_sizes, int n_in,
                              void* d_out, int out_size, void* d_ws, size_t ws_size,
                              hipStream_t stream){
  const float* x    = (const float*)d_in[0];
  const float* xsrc = (const float*)d_in[1];
  const float* loc  = (const float*)d_in[2];
  const float* csrc = (const float*)d_in[3];
  const float* qw   = (const float*)d_in[4];
  const float* kvw  = (const float*)d_in[5];
  const float* srw  = (const float*)d_in[6];
  const float* srb  = (const float*)d_in[7];
  const float* nw   = (const float*)d_in[8];
  const float* nbv  = (const float*)d_in[9];
  const float* pw   = (const float*)d_in[10];
  const float* pb   = (const float*)d_in[11];
  float* out = (float*)d_out;                  // reference output dtype = f32
  float* ws = (float*)d_ws;

  // adaptive workspace: full 8-batch layout needs 36.7MB; per-batch fallback.
  size_t full_floats = 8ull*(GH*GW*NC + GH*GW + GM + GM + GM*NC)
                     + 8ull*(GM + 4*GM*NC);
  int nb    = (ws_size >= full_floats*sizeof(float)) ? 8 : 1;
  int iters = 8 / nb;

  size_t SZf = (size_t)nb*GH*GW*NC;
  size_t SZc = (size_t)nb*GH*GW;
  size_t SZs = (size_t)nb*GM;
  size_t SZx = (size_t)nb*GM*NC;
  size_t of_feat = 0;
  size_t of_cnt  = of_feat + SZf;
  size_t of_csum = of_cnt  + SZc;
  size_t of_ccnt = of_csum + SZs;
  size_t of_xs0  = of_ccnt + SZs;
  size_t zero_sz = of_xs0  + SZx;
  size_t of_conf = zero_sz;
  size_t of_xs   = of_conf + SZs;
  size_t of_kt   = of_xs   + SZx;
  size_t of_vp   = of_kt   + SZx;
  size_t of_vt   = of_vp   + SZx;

  for (int it = 0; it < iters; ++it){
    size_t b0 = (size_t)it*nb;
    const float* xsrc_b = xsrc + b0*NN*NC;
    const float* loc_b  = loc  + b0*NN*2;
    const float* csrc_b = csrc + b0*NN;
    const float* x_b    = x    + b0*NN*NC;
    float*       out_b  = out  + b0*NN*NC;

    hipMemsetAsync(ws, 0, zero_sz*sizeof(float), stream);
    k_scatter_feat <<<nb*NN*NC/256, 256, 0, stream>>>(xsrc_b, loc_b, ws+of_feat);
    k_scatter_aux  <<<nb*NN/256,    256, 0, stream>>>(loc_b, csrc_b, ws+of_cnt, ws+of_csum, ws+of_ccnt);
    k_finalize_feat<<<nb*GH*GW*NC/256, 256, 0, stream>>>(ws+of_feat, ws+of_cnt);
    k_finalize_conf<<<(nb*GM+255)/256, 256, 0, stream>>>(ws+of_csum, ws+of_ccnt, ws+of_conf);
    k_fill         <<<nb*GH*GW/256, 256, 0, stream>>>(ws+of_cnt, ws+of_feat);
    k_srconv_naive <<<nb*GM*NC/256, 256, 0, stream>>>(ws+of_feat, srw, ws+of_xs0);
    k_ln           <<<nb*GM/4,      256, 0, stream>>>(ws+of_xs0, srb, nw, nbv, ws+of_xs);
    k_kv1          <<<nb*GM*NC/256, 256, 0, stream>>>(ws+of_xs, kvw, ws+of_kt, ws+of_vt);
    k_kv2          <<<nb*GM*NC/256, 256, 0, stream>>>(ws+of_vt, pw, ws+of_vp);
    k_attn_naive   <<<nb*NN/4,      256, 0, stream>>>(x_b, qw, ws+of_kt, ws+of_vp, ws+of_conf, pb, out_b);
  }
}

// Round 6
// 746.152 us; speedup vs baseline: 1.4913x; 1.4913x over previous
//
#include <hip/hip_runtime.h>
#include <hip/hip_bf16.h>

#define NN 16384
#define NC 64
#define GH 128
#define GW 128
#define GM 256

static __device__ __forceinline__ int reflect128(int i){
  if (i < 0) i = -i;
  if (i > 127) i = 254 - i;
  return i;
}

// px = round(0.5*(loc+1)*S - 0.5): (loc+1) rounds once; *S2 (pow2) exact;
// -0.5 rounds once == reference's f32 sequence bit-for-bit.
static __device__ __forceinline__ int cell_of(float l, float S2, int hi){
  l = fminf(fmaxf(l, -1.f), 1.f);
  float u = l + 1.f;
  int p = (int)rintf(u*S2 - 0.5f);
  return min(max(p,0),hi);
}

__global__ __launch_bounds__(256) void k_scatter_feat(
    const float* __restrict__ xsrc, const float* __restrict__ loc,
    float* __restrict__ featg){
  int gid = blockIdx.x*256 + threadIdx.x;
  int t = gid >> 6;
  int b = t >> 14;
  int px = cell_of(loc[2*t],   64.f, 127);
  int py = cell_of(loc[2*t+1], 64.f, 127);
  int cell = (b*GH + py)*GW + px;
  atomicAdd(&featg[cell*NC + (gid & 63)], xsrc[gid]);
}

__global__ __launch_bounds__(256) void k_scatter_aux(
    const float* __restrict__ loc, const float* __restrict__ csrc,
    float* __restrict__ cnt, float* __restrict__ csum, float* __restrict__ ccnt){
  int t = blockIdx.x*256 + threadIdx.x;
  int b = t >> 14;
  int px = cell_of(loc[2*t],   64.f, 127);
  int py = cell_of(loc[2*t+1], 64.f, 127);
  atomicAdd(&cnt[(b*GH+py)*GW+px], 1.0f);
  int qx = cell_of(loc[2*t],   8.f, 15);
  int qy = cell_of(loc[2*t+1], 8.f, 15);
  int cell = b*GM + qy*16 + qx;
  atomicAdd(&csum[cell], csrc[t]);
  atomicAdd(&ccnt[cell], 1.0f);
}

__global__ __launch_bounds__(256) void k_finalize_feat(
    float* __restrict__ featg, const float* __restrict__ cnt){
  int gid = blockIdx.x*256 + threadIdx.x;
  float cn = cnt[gid>>6];
  float v  = featg[gid];
  featg[gid] = (cn > 0.f) ? v/(cn+1e-6f) : 0.f;
}

__global__ __launch_bounds__(256) void k_finalize_conf(
    const float* __restrict__ csum, const float* __restrict__ ccnt,
    float* __restrict__ conf){
  int i = blockIdx.x*256 + threadIdx.x;
  float cn = ccnt[i];
  conf[i] = (cn > 0.f) ? csum[i]/(cn+1e-6f) : 0.f;
}

// 9x9 gaussian hole fill; writes only cnt==0 pixels (taps read only cnt>0).
__global__ __launch_bounds__(256) void k_fill(
    const float* __restrict__ cnt, float* __restrict__ feat){
  int p = blockIdx.x*256 + threadIdx.x;
  if (cnt[p] > 0.f) return;
  int b = p>>14, py=(p>>7)&127, px=p&127;
  const float fn = 0.039788735772973836f;    // 1/(2*pi*var), var=4
  float g1[9];
  #pragma unroll
  for (int i=0;i<9;++i){ float d=(float)i-4.f; g1[i]=__expf(-d*d*0.125f); }
  float4 acc[16];
  #pragma unroll
  for (int i=0;i<16;++i) acc[i]=make_float4(0.f,0.f,0.f,0.f);
  float msum=0.f;
  for (int dy=0; dy<9; ++dy){
    int iy = reflect128(py-4+dy);
    for (int dx=0; dx<9; ++dx){
      int ix = reflect128(px-4+dx);
      int q  = (b*GH+iy)*GW+ix;
      if (cnt[q] <= 0.f) continue;
      float wn = g1[dy]*g1[dx]*fn;
      msum += wn;
      const float4* fr = (const float4*)&feat[q*NC];
      #pragma unroll
      for (int k=0;k<16;++k){
        float4 vv = fr[k];
        acc[k].x += wn*vv.x; acc[k].y += wn*vv.y;
        acc[k].z += wn*vv.z; acc[k].w += wn*vv.w;
      }
    }
  }
  if (msum <= 0.f) return;
  float inv = 1.f/(msum + 1e-6f);
  float4* o = (float4*)&feat[p*NC];
  #pragma unroll
  for (int k=0;k<16;++k)
    o[k] = make_float4(acc[k].x*inv, acc[k].y*inv, acc[k].z*inv, acc[k].w*inv);
}

// stride-8 8x8 conv as split-K GEMM: M=nb*256 patches, K split by kh, N=64
__global__ __launch_bounds__(256) void k_srconv(
    const float* __restrict__ feat, const float* __restrict__ srw,
    float* __restrict__ xs0){
  alignas(16) __shared__ float A[64*65];
  alignas(16) __shared__ float Bs[64*64];
  int mt = blockIdx.x, kh = blockIdx.y;
  int t = threadIdx.x;
  int tm = t>>4, tn = t&15;
  float acc[4][4] = {{0.f}};
  for (int kc=0; kc<8; ++kc){
    __syncthreads();
    for (int idx=t; idx<4096; idx+=256){
      int mr = idx>>6, kk = idx&63;
      int m = mt*64+mr;
      int b = m>>8, oh=(m>>4)&15, ow=m&15;
      A[mr*65+kk] = feat[(((b*GH)+(oh*8+kh))*GW + ow*8)*NC + kc*64 + kk];
    }
    for (int idx=t; idx<4096; idx+=256)
      Bs[idx] = srw[(kh*512 + kc*64)*64 + idx];
    __syncthreads();
    for (int kk=0; kk<64; ++kk){
      float4 bv = *(const float4*)&Bs[kk*64 + tn*4];
      #pragma unroll
      for (int i=0;i<4;++i){
        float av = A[(tm*4+i)*65 + kk];
        acc[i][0] += av*bv.x; acc[i][1] += av*bv.y;
        acc[i][2] += av*bv.z; acc[i][3] += av*bv.w;
      }
    }
  }
  #pragma unroll
  for (int i=0;i<4;++i)
    #pragma unroll
    for (int j=0;j<4;++j)
      atomicAdd(&xs0[(mt*64+tm*4+i)*64 + tn*4+j], acc[i][j]);
}

// layernorm(xs0 + sr_b) -> xs   (wave per row)
__global__ __launch_bounds__(256) void k_ln(
    const float* __restrict__ xs0, const float* __restrict__ srb,
    const float* __restrict__ nw, const float* __restrict__ nbv,
    float* __restrict__ xs){
  int row  = blockIdx.x*4 + (threadIdx.x>>6);
  int lane = threadIdx.x & 63;
  float v = xs0[row*64+lane] + srb[lane];
  float s = v;
  #pragma unroll
  for (int off=32; off; off>>=1) s += __shfl_xor(s, off, 64);
  float mean = s*(1.f/64.f);
  float d = v - mean;
  float s2 = d*d;
  #pragma unroll
  for (int off=32; off; off>>=1) s2 += __shfl_xor(s2, off, 64);
  float var = s2*(1.f/64.f);
  xs[row*64+lane] = d*(1.f/sqrtf(var+1e-5f))*nw[lane] + nbv[lane];
}

// kv: thread per (b,m,d)
__global__ __launch_bounds__(256) void k_kv1(
    const float* __restrict__ xs, const float* __restrict__ kvw,
    float* __restrict__ kT, float* __restrict__ vt){
  int gid = blockIdx.x*256 + threadIdx.x;
  int r = gid >> 6, d = gid & 63;
  int b = r >> 8, m = r & 255;
  const float* xr = &xs[r*64];
  float ka=0.f, va=0.f;
  for (int c=0;c<64;++c){
    float xc = xr[c];
    ka += xc*kvw[d*64+c];
    va += xc*kvw[(64+d)*64+c];
  }
  kT[(b*64+d)*GM + m] = ka;                    // [b][d][m]
  vt[gid] = va;                                // [b*256+m][d]
}

// vp = v @ proj_w^T : thread per (b,m,co)
__global__ __launch_bounds__(256) void k_kv2(
    const float* __restrict__ vt, const float* __restrict__ projw,
    float* __restrict__ vp){
  int gid = blockIdx.x*256 + threadIdx.x;
  int r = gid >> 6, co = gid & 63;
  const float* vr = &vt[r*64];
  float acc = 0.f;
  for (int d=0; d<64; ++d)
    acc += vr[d]*projw[co*64+d];
  vp[gid] = acc;                               // [b*256+m][co]
}

// fused q-proj + attention (proj folded into vp); 64 q-rows per block, f32 out
__global__ __launch_bounds__(256) void k_attn(
    const float* __restrict__ x, const float* __restrict__ qw,
    const float* __restrict__ kT, const float* __restrict__ vp,
    const float* __restrict__ conf, const float* __restrict__ projb,
    float* __restrict__ out){
  alignas(16) __shared__ float KT[64*256];    // [d][m]
  alignas(16) __shared__ float VPQ[256*64];   // [m4][c][j] : vp[4*m4+j][c]
  alignas(16) __shared__ float CF[256];
  alignas(16) __shared__ float SCR[4224];     // qwT during setup; wave scratch after
  int t = threadIdx.x;
  int b    = blockIdx.x >> 8;
  int row0 = (blockIdx.x & 255) << 6;
  for (int i=t; i<16384; i+=256) KT[i] = kT[b*16384+i];
  for (int i=t; i<16384; i+=256){
    int m = i>>6, c = i&63;
    VPQ[((m>>2)*64 + c)*4 + (m&3)] = vp[b*16384+i];
  }
  CF[t & 255] = conf[b*GM + (t & 255)];
  for (int i=t; i<4096; i+=256){
    int d = i>>6, c = i&63;
    SCR[c*66+d] = qw[i];                      // qwT[c][d]
  }
  __syncthreads();
  int w = t>>6, lane = t&63;
  float q[16];
  {
    const float* xb = x + (size_t)(b*NN + row0 + w*16)*NC;
    #pragma unroll
    for (int r=0;r<16;++r) q[r]=0.f;
    for (int c=0;c<64;++c){
      float wv = SCR[c*66+lane];
      #pragma unroll
      for (int r=0;r<16;++r)
        q[r] += xb[r*64+c]*wv;                // uniform-address x loads (L1)
    }
  }
  __syncthreads();                            // qwT dead; SCR -> wave scratch
  float4 cf4 = *(const float4*)&CF[lane<<2];
  float pbv  = projb[lane];
  float* scr = SCR + w*1056;                  // 4 rows x 264 floats
  for (int g=0; g<4; ++g){
    #pragma unroll
    for (int r=0;r<4;++r) scr[r*264+lane] = q[g*4+r];
    float s[4][4];
    #pragma unroll
    for (int r=0;r<4;++r){ s[r][0]=0.f; s[r][1]=0.f; s[r][2]=0.f; s[r][3]=0.f; }
    for (int d4=0; d4<16; ++d4){
      float qq[4][4];
      #pragma unroll
      for (int r=0;r<4;++r)
        *(float4*)&qq[r][0] = *(const float4*)&scr[r*264 + (d4<<2)];
      #pragma unroll
      for (int dj=0;dj<4;++dj){
        float4 kk = *(const float4*)&KT[(d4*4+dj)*256 + (lane<<2)];
        #pragma unroll
        for (int r=0;r<4;++r){
          float qa = qq[r][dj];
          s[r][0] += qa*kk.x; s[r][1] += qa*kk.y;
          s[r][2] += qa*kk.z; s[r][3] += qa*kk.w;
        }
      }
    }
    #pragma unroll
    for (int r=0;r<4;++r){
      float s0 = s[r][0]*0.125f + cf4.x;
      float s1 = s[r][1]*0.125f + cf4.y;
      float s2 = s[r][2]*0.125f + cf4.z;
      float s3 = s[r][3]*0.125f + cf4.w;
      float mx = fmaxf(fmaxf(s0,s1), fmaxf(s2,s3));
      #pragma unroll
      for (int off=32; off; off>>=1) mx = fmaxf(mx, __shfl_xor(mx, off, 64));
      float e0=__expf(s0-mx), e1=__expf(s1-mx), e2=__expf(s2-mx), e3=__expf(s3-mx);
      float sm = e0+e1+e2+e3;
      #pragma unroll
      for (int off=32; off; off>>=1) sm += __shfl_xor(sm, off, 64);
      float inv = 1.f/sm;
      *(float4*)&scr[r*264 + (lane<<2)] = make_float4(e0*inv, e1*inv, e2*inv, e3*inv);
    }
    float acc[4] = {0.f,0.f,0.f,0.f};
    for (int m4=0; m4<64; ++m4){
      float4 v4 = *(const float4*)&VPQ[((m4<<6)+lane)<<2];
      #pragma unroll
      for (int r=0;r<4;++r){
        float4 p4 = *(const float4*)&scr[r*264 + (m4<<2)];
        acc[r] += p4.x*v4.x + p4.y*v4.y + p4.z*v4.z + p4.w*v4.w;
      }
    }
    size_t ob = (size_t)(b*NN + row0 + (w<<4) + (g<<2))*NC;
    #pragma unroll
    for (int r=0;r<4;++r)
      out[ob + r*64 + lane] = acc[r] + pbv;
  }
}

extern "C" void kernel_launch(void* const* d_in, const int* in_sizes, int n_in,
                              void* d_out, int out_size, void* d_ws, size_t ws_size,
                              hipStream_t stream){
  const float* x    = (const float*)d_in[0];
  const float* xsrc = (const float*)d_in[1];
  const float* loc  = (const float*)d_in[2];
  const float* csrc = (const float*)d_in[3];
  const float* qw   = (const float*)d_in[4];
  const float* kvw  = (const float*)d_in[5];
  const float* srw  = (const float*)d_in[6];
  const float* srb  = (const float*)d_in[7];
  const float* nw   = (const float*)d_in[8];
  const float* nbv  = (const float*)d_in[9];
  const float* pw   = (const float*)d_in[10];
  const float* pb   = (const float*)d_in[11];
  float* out = (float*)d_out;                  // reference output dtype = f32
  float* ws = (float*)d_ws;

  size_t full_floats = 8ull*(GH*GW*NC + GH*GW + GM + GM + GM*NC)
                     + 8ull*(GM + 4*GM*NC);
  int nb    = (ws_size >= full_floats*sizeof(float)) ? 8 : 1;
  int iters = 8 / nb;

  size_t SZf = (size_t)nb*GH*GW*NC;
  size_t SZc = (size_t)nb*GH*GW;
  size_t SZs = (size_t)nb*GM;
  size_t SZx = (size_t)nb*GM*NC;
  size_t of_feat = 0;
  size_t of_cnt  = of_feat + SZf;
  size_t of_csum = of_cnt  + SZc;
  size_t of_ccnt = of_csum + SZs;
  size_t of_xs0  = of_ccnt + SZs;
  size_t zero_sz = of_xs0  + SZx;
  size_t of_conf = zero_sz;
  size_t of_xs   = of_conf + SZs;
  size_t of_kt   = of_xs   + SZx;
  size_t of_vp   = of_kt   + SZx;
  size_t of_vt   = of_vp   + SZx;

  for (int it = 0; it < iters; ++it){
    size_t b0 = (size_t)it*nb;
    const float* xsrc_b = xsrc + b0*NN*NC;
    const float* loc_b  = loc  + b0*NN*2;
    const float* csrc_b = csrc + b0*NN;
    const float* x_b    = x    + b0*NN*NC;
    float*       out_b  = out  + b0*NN*NC;

    hipMemsetAsync(ws, 0, zero_sz*sizeof(float), stream);
    k_scatter_feat <<<nb*NN*NC/256, 256, 0, stream>>>(xsrc_b, loc_b, ws+of_feat);
    k_scatter_aux  <<<nb*NN/256,    256, 0, stream>>>(loc_b, csrc_b, ws+of_cnt, ws+of_csum, ws+of_ccnt);
    k_finalize_feat<<<nb*GH*GW*NC/256, 256, 0, stream>>>(ws+of_feat, ws+of_cnt);
    k_finalize_conf<<<(nb*GM+255)/256, 256, 0, stream>>>(ws+of_csum, ws+of_ccnt, ws+of_conf);
    k_fill         <<<nb*GH*GW/256, 256, 0, stream>>>(ws+of_cnt, ws+of_feat);
    dim3 gconv(nb*GM/64, 8);
    k_srconv       <<<gconv,        256, 0, stream>>>(ws+of_feat, srw, ws+of_xs0);
    k_ln           <<<nb*GM/4,      256, 0, stream>>>(ws+of_xs0, srb, nw, nbv, ws+of_xs);
    k_kv1          <<<nb*GM*NC/256, 256, 0, stream>>>(ws+of_xs, kvw, ws+of_kt, ws+of_vt);
    k_kv2          <<<nb*GM*NC/256, 256, 0, stream>>>(ws+of_vt, pw, ws+of_vp);
    k_attn         <<<nb*NN/64,     256, 0, stream>>>(x_b, qw, ws+of_kt, ws+of_vp, ws+of_conf, pb, out_b);
  }
}

// Round 7
// 725.978 us; speedup vs baseline: 1.5327x; 1.0278x over previous
//
#include <hip/hip_runtime.h>
#include <hip/hip_bf16.h>

#define NN 16384
#define NC 64
#define GH 128
#define GW 128
#define GM 256

static __device__ __forceinline__ int reflect128(int i){
  if (i < 0) i = -i;
  if (i > 127) i = 254 - i;
  return i;
}

// px = round(0.5*(loc+1)*S - 0.5): (loc+1) rounds once; *S2 (pow2) exact;
// -0.5 rounds once == reference's f32 sequence bit-for-bit.
static __device__ __forceinline__ int cell_of(float l, float S2, int hi){
  l = fminf(fmaxf(l, -1.f), 1.f);
  float u = l + 1.f;
  int p = (int)rintf(u*S2 - 0.5f);
  return min(max(p,0),hi);
}

__global__ __launch_bounds__(256) void k_scatter_feat(
    const float* __restrict__ xsrc, const float* __restrict__ loc,
    float* __restrict__ featg){
  int gid = blockIdx.x*256 + threadIdx.x;
  int t = gid >> 6;
  int b = t >> 14;
  int px = cell_of(loc[2*t],   64.f, 127);
  int py = cell_of(loc[2*t+1], 64.f, 127);
  int cell = (b*GH + py)*GW + px;
  atomicAdd(&featg[cell*NC + (gid & 63)], xsrc[gid]);
}

__global__ __launch_bounds__(256) void k_scatter_aux(
    const float* __restrict__ loc, const float* __restrict__ csrc,
    float* __restrict__ cnt, float* __restrict__ csum, float* __restrict__ ccnt){
  int t = blockIdx.x*256 + threadIdx.x;
  int b = t >> 14;
  int px = cell_of(loc[2*t],   64.f, 127);
  int py = cell_of(loc[2*t+1], 64.f, 127);
  atomicAdd(&cnt[(b*GH+py)*GW+px], 1.0f);
  int qx = cell_of(loc[2*t],   8.f, 15);
  int qy = cell_of(loc[2*t+1], 8.f, 15);
  int cell = b*GM + qy*16 + qx;
  atomicAdd(&csum[cell], csrc[t]);
  atomicAdd(&ccnt[cell], 1.0f);
}

__global__ __launch_bounds__(256) void k_finalize_feat(
    float* __restrict__ featg, const float* __restrict__ cnt){
  int gid = blockIdx.x*256 + threadIdx.x;
  float cn = cnt[gid>>6];
  float v  = featg[gid];
  featg[gid] = (cn > 0.f) ? v/(cn+1e-6f) : 0.f;
}

__global__ __launch_bounds__(256) void k_finalize_conf(
    const float* __restrict__ csum, const float* __restrict__ ccnt,
    float* __restrict__ conf){
  int i = blockIdx.x*256 + threadIdx.x;
  float cn = ccnt[i];
  conf[i] = (cn > 0.f) ? csum[i]/(cn+1e-6f) : 0.f;
}

// 9x9 gaussian hole fill; writes only cnt==0 pixels (taps read only cnt>0).
__global__ __launch_bounds__(256) void k_fill(
    const float* __restrict__ cnt, float* __restrict__ feat){
  int p = blockIdx.x*256 + threadIdx.x;
  if (cnt[p] > 0.f) return;
  int b = p>>14, py=(p>>7)&127, px=p&127;
  const float fn = 0.039788735772973836f;    // 1/(2*pi*var), var=4
  float g1[9];
  #pragma unroll
  for (int i=0;i<9;++i){ float d=(float)i-4.f; g1[i]=__expf(-d*d*0.125f); }
  float4 acc[16];
  #pragma unroll
  for (int i=0;i<16;++i) acc[i]=make_float4(0.f,0.f,0.f,0.f);
  float msum=0.f;
  for (int dy=0; dy<9; ++dy){
    int iy = reflect128(py-4+dy);
    for (int dx=0; dx<9; ++dx){
      int ix = reflect128(px-4+dx);
      int q  = (b*GH+iy)*GW+ix;
      if (cnt[q] <= 0.f) continue;
      float wn = g1[dy]*g1[dx]*fn;
      msum += wn;
      const float4* fr = (const float4*)&feat[q*NC];
      #pragma unroll
      for (int k=0;k<16;++k){
        float4 vv = fr[k];
        acc[k].x += wn*vv.x; acc[k].y += wn*vv.y;
        acc[k].z += wn*vv.z; acc[k].w += wn*vv.w;
      }
    }
  }
  if (msum <= 0.f) return;
  float inv = 1.f/(msum + 1e-6f);
  float4* o = (float4*)&feat[p*NC];
  #pragma unroll
  for (int k=0;k<16;++k)
    o[k] = make_float4(acc[k].x*inv, acc[k].y*inv, acc[k].z*inv, acc[k].w*inv);
}

// stride-8 8x8 conv as split-K GEMM: M=nb*256 patches, K split by kh, N=64
__global__ __launch_bounds__(256) void k_srconv(
    const float* __restrict__ feat, const float* __restrict__ srw,
    float* __restrict__ xs0){
  alignas(16) __shared__ float A[64*65];
  alignas(16) __shared__ float Bs[64*64];
  int mt = blockIdx.x, kh = blockIdx.y;
  int t = threadIdx.x;
  int tm = t>>4, tn = t&15;
  float acc[4][4] = {{0.f}};
  for (int kc=0; kc<8; ++kc){
    __syncthreads();
    for (int idx=t; idx<4096; idx+=256){
      int mr = idx>>6, kk = idx&63;
      int m = mt*64+mr;
      int b = m>>8, oh=(m>>4)&15, ow=m&15;
      A[mr*65+kk] = feat[(((b*GH)+(oh*8+kh))*GW + ow*8)*NC + kc*64 + kk];
    }
    for (int idx=t; idx<4096; idx+=256)
      Bs[idx] = srw[(kh*512 + kc*64)*64 + idx];
    __syncthreads();
    for (int kk=0; kk<64; ++kk){
      float4 bv = *(const float4*)&Bs[kk*64 + tn*4];
      #pragma unroll
      for (int i=0;i<4;++i){
        float av = A[(tm*4+i)*65 + kk];
        acc[i][0] += av*bv.x; acc[i][1] += av*bv.y;
        acc[i][2] += av*bv.z; acc[i][3] += av*bv.w;
      }
    }
  }
  #pragma unroll
  for (int i=0;i<4;++i)
    #pragma unroll
    for (int j=0;j<4;++j)
      atomicAdd(&xs0[(mt*64+tm*4+i)*64 + tn*4+j], acc[i][j]);
}

// layernorm(xs0 + sr_b) -> xs   (wave per row)
__global__ __launch_bounds__(256) void k_ln(
    const float* __restrict__ xs0, const float* __restrict__ srb,
    const float* __restrict__ nw, const float* __restrict__ nbv,
    float* __restrict__ xs){
  int row  = blockIdx.x*4 + (threadIdx.x>>6);
  int lane = threadIdx.x & 63;
  float v = xs0[row*64+lane] + srb[lane];
  float s = v;
  #pragma unroll
  for (int off=32; off; off>>=1) s += __shfl_xor(s, off, 64);
  float mean = s*(1.f/64.f);
  float d = v - mean;
  float s2 = d*d;
  #pragma unroll
  for (int off=32; off; off>>=1) s2 += __shfl_xor(s2, off, 64);
  float var = s2*(1.f/64.f);
  xs[row*64+lane] = d*(1.f/sqrtf(var+1e-5f))*nw[lane] + nbv[lane];
}

// kv: thread per (r,d): raw k and v rows.
__global__ __launch_bounds__(256) void k_kv1(
    const float* __restrict__ xs, const float* __restrict__ kvw,
    float* __restrict__ kraw, float* __restrict__ vraw){
  int gid = blockIdx.x*256 + threadIdx.x;
  int r = gid >> 6, d = gid & 63;
  const float* xr = &xs[r*64];
  float ka=0.f, va=0.f;
  for (int c=0;c<64;++c){
    float xc = xr[c];
    ka += xc*kvw[d*64+c];
    va += xc*kvw[(64+d)*64+c];
  }
  kraw[gid] = ka;                              // [r][d]
  vraw[gid] = va;                              // [r][d]
}

// fold q_w into K (K' = k @ q_w) and proj_w into V (Vp = v @ proj_w^T).
// kqT layout [b][c][m]; vpq layout [b][m4][c][j] (j = m&3) for b128 PV reads.
__global__ __launch_bounds__(256) void k_kvproj(
    const float* __restrict__ kraw, const float* __restrict__ vraw,
    const float* __restrict__ qw, const float* __restrict__ pw,
    float* __restrict__ kqT, float* __restrict__ vpq){
  int gid = blockIdx.x*256 + threadIdx.x;
  int r = gid >> 6, c = gid & 63;
  int b = r >> 8, m = r & 255;
  const float* kr = &kraw[r*64];
  const float* vr = &vraw[r*64];
  float ak=0.f, av=0.f;
  for (int i=0;i<64;++i){
    ak += kr[i]*qw[i*64+c];                    // K'[m][c] = sum_i k_i qw[i][c]
    av += vr[i]*pw[c*64+i];                    // Vp[m][c] = sum_i v_i pw[c][i]
  }
  kqT[(b*64+c)*GM + m] = ak;
  vpq[b*16384 + (m>>2)*256 + c*4 + (m&3)] = av;
}

#define FMA4(S,XS,KK) { S.x += (XS)*(KK).x; S.y += (XS)*(KK).y; \
                        S.z += (XS)*(KK).z; S.w += (XS)*(KK).w; }

// attention v2: 4 waves x 16 q-rows; logits in registers (m = 4*lane+j);
// K'/Vp read once per wave from L2; LDS only for e-values (wave-private) + conf.
__global__ __launch_bounds__(256) void k_attn2(
    const float* __restrict__ x, const float* __restrict__ kqT,
    const float* __restrict__ vpq, const float* __restrict__ conf,
    const float* __restrict__ projb, float* __restrict__ out){
  __shared__ float PS[4][16*256];              // e-values, wave-private
  __shared__ float CF[256];
  int t = threadIdx.x, w = t>>6, lane = t&63;
  int b    = blockIdx.x >> 8;
  int row0 = (blockIdx.x & 255) << 6;
  CF[t] = conf[b*GM + t];
  __syncthreads();

  const float* xw = x + (size_t)(b*NN + row0 + w*16)*NC;
  const float* KT = kqT + b*16384;
  float4 s4[16];
  #pragma unroll
  for (int r=0;r<16;++r) s4[r] = make_float4(0.f,0.f,0.f,0.f);

  #pragma unroll 4
  for (int d4=0; d4<16; ++d4){
    float4 kk0 = *(const float4*)&KT[(d4*4+0)*GM + (lane<<2)];
    float4 kk1 = *(const float4*)&KT[(d4*4+1)*GM + (lane<<2)];
    float4 kk2 = *(const float4*)&KT[(d4*4+2)*GM + (lane<<2)];
    float4 kk3 = *(const float4*)&KT[(d4*4+3)*GM + (lane<<2)];
    #pragma unroll
    for (int r=0;r<16;++r){
      float4 xx = *(const float4*)&xw[r*64 + (d4<<2)];  // uniform addr -> L1
      FMA4(s4[r], xx.x, kk0);
      FMA4(s4[r], xx.y, kk1);
      FMA4(s4[r], xx.z, kk2);
      FMA4(s4[r], xx.w, kk3);
    }
  }

  // softmax (no max-subtract: |s*0.125+conf| < ~1, exp safe; ratio identical)
  float inv[16];
  float4 cf4 = *(const float4*)&CF[lane<<2];
  #pragma unroll
  for (int r=0;r<16;++r){
    float4 e;
    e.x = __expf(fmaf(s4[r].x, 0.125f, cf4.x));
    e.y = __expf(fmaf(s4[r].y, 0.125f, cf4.y));
    e.z = __expf(fmaf(s4[r].z, 0.125f, cf4.z));
    e.w = __expf(fmaf(s4[r].w, 0.125f, cf4.w));
    float sm = e.x+e.y+e.z+e.w;
    #pragma unroll
    for (int off=32; off; off>>=1) sm += __shfl_xor(sm, off, 64);
    inv[r] = 1.f/sm;
    *(float4*)&PS[w][r*256 + (lane<<2)] = e;   // PS[w][r][m], m=4*lane+j
  }
  // no barrier: PS is wave-private (compiler inserts lgkmcnt for own data dep)

  float acc[16];
  #pragma unroll
  for (int r=0;r<16;++r) acc[r]=0.f;
  const float* VP = vpq + b*16384;
  #pragma unroll 4
  for (int m4=0; m4<64; ++m4){
    float4 v4 = *(const float4*)&VP[m4*256 + (lane<<2)]; // c=lane, 4 m's
    #pragma unroll
    for (int r=0;r<16;++r){
      float4 p4 = *(const float4*)&PS[w][r*256 + (m4<<2)]; // broadcast
      acc[r] += p4.x*v4.x + p4.y*v4.y + p4.z*v4.z + p4.w*v4.w;
    }
  }

  float pbv = projb[lane];
  size_t ob = (size_t)(b*NN + row0 + w*16)*NC;
  #pragma unroll
  for (int r=0;r<16;++r)
    out[ob + r*64 + lane] = fmaf(acc[r], inv[r], pbv);
}

extern "C" void kernel_launch(void* const* d_in, const int* in_sizes, int n_in,
                              void* d_out, int out_size, void* d_ws, size_t ws_size,
                              hipStream_t stream){
  const float* x    = (const float*)d_in[0];
  const float* xsrc = (const float*)d_in[1];
  const float* loc  = (const float*)d_in[2];
  const float* csrc = (const float*)d_in[3];
  const float* qw   = (const float*)d_in[4];
  const float* kvw  = (const float*)d_in[5];
  const float* srw  = (const float*)d_in[6];
  const float* srb  = (const float*)d_in[7];
  const float* nw   = (const float*)d_in[8];
  const float* nbv  = (const float*)d_in[9];
  const float* pw   = (const float*)d_in[10];
  const float* pb   = (const float*)d_in[11];
  float* out = (float*)d_out;                  // reference output dtype = f32
  float* ws = (float*)d_ws;

  size_t full_floats = 8ull*(GH*GW*NC + GH*GW + GM + GM + GM*NC)  // zeroed
                     + 8ull*(GM + 5*GM*NC);    // conf/xs/kraw/vraw/kqT/vpq
  int nb    = (ws_size >= full_floats*sizeof(float)) ? 8 : 1;
  int iters = 8 / nb;

  size_t SZf = (size_t)nb*GH*GW*NC;
  size_t SZc = (size_t)nb*GH*GW;
  size_t SZs = (size_t)nb*GM;
  size_t SZx = (size_t)nb*GM*NC;
  size_t of_feat = 0;
  size_t of_cnt  = of_feat + SZf;
  size_t of_csum = of_cnt  + SZc;
  size_t of_ccnt = of_csum + SZs;
  size_t of_xs0  = of_ccnt + SZs;
  size_t zero_sz = of_xs0  + SZx;
  size_t of_conf = zero_sz;
  size_t of_xs   = of_conf + SZs;
  size_t of_kr   = of_xs   + SZx;
  size_t of_vr   = of_kr   + SZx;
  size_t of_kqt  = of_vr   + SZx;
  size_t of_vpq  = of_kqt  + SZx;

  for (int it = 0; it < iters; ++it){
    size_t b0 = (size_t)it*nb;
    const float* xsrc_b = xsrc + b0*NN*NC;
    const float* loc_b  = loc  + b0*NN*2;
    const float* csrc_b = csrc + b0*NN;
    const float* x_b    = x    + b0*NN*NC;
    float*       out_b  = out  + b0*NN*NC;

    hipMemsetAsync(ws, 0, zero_sz*sizeof(float), stream);
    k_scatter_feat <<<nb*NN*NC/256, 256, 0, stream>>>(xsrc_b, loc_b, ws+of_feat);
    k_scatter_aux  <<<nb*NN/256,    256, 0, stream>>>(loc_b, csrc_b, ws+of_cnt, ws+of_csum, ws+of_ccnt);
    k_finalize_feat<<<nb*GH*GW*NC/256, 256, 0, stream>>>(ws+of_feat, ws+of_cnt);
    k_finalize_conf<<<(nb*GM+255)/256, 256, 0, stream>>>(ws+of_csum, ws+of_ccnt, ws+of_conf);
    k_fill         <<<nb*GH*GW/256, 256, 0, stream>>>(ws+of_cnt, ws+of_feat);
    dim3 gconv(nb*GM/64, 8);
    k_srconv       <<<gconv,        256, 0, stream>>>(ws+of_feat, srw, ws+of_xs0);
    k_ln           <<<nb*GM/4,      256, 0, stream>>>(ws+of_xs0, srb, nw, nbv, ws+of_xs);
    k_kv1          <<<nb*GM*NC/256, 256, 0, stream>>>(ws+of_xs, kvw, ws+of_kr, ws+of_vr);
    k_kvproj       <<<nb*GM*NC/256, 256, 0, stream>>>(ws+of_kr, ws+of_vr, qw, pw, ws+of_kqt, ws+of_vpq);
    k_attn2        <<<nb*NN/64,     256, 0, stream>>>(x_b, ws+of_kqt, ws+of_vpq, ws+of_conf, pb, out_b);
  }
}

// Round 8
// 374.346 us; speedup vs baseline: 2.9725x; 1.9393x over previous
//
#include <hip/hip_runtime.h>
#include <hip/hip_bf16.h>

#define NN 16384
#define NC 64
#define GH 128
#define GW 128
#define GM 256

typedef __attribute__((ext_vector_type(8))) short bf16x8;
typedef __attribute__((ext_vector_type(4))) float f32x4;

static __device__ __forceinline__ int reflect128(int i){
  if (i < 0) i = -i;
  if (i > 127) i = 254 - i;
  return i;
}

static __device__ __forceinline__ ushort f2bf(float f){
  union { float f; unsigned u; } v; v.f = f;
  unsigned r = v.u + 0x7fffu + ((v.u >> 16) & 1u);   // RNE, no NaN inputs
  return (ushort)(r >> 16);
}

// px = round(0.5*(loc+1)*S - 0.5): (loc+1) rounds once; *S2 (pow2) exact;
// -0.5 rounds once == reference's f32 sequence bit-for-bit.
static __device__ __forceinline__ int cell_of(float l, float S2, int hi){
  l = fminf(fmaxf(l, -1.f), 1.f);
  float u = l + 1.f;
  int p = (int)rintf(u*S2 - 0.5f);
  return min(max(p,0),hi);
}

__global__ __launch_bounds__(256) void k_scatter_feat(
    const float* __restrict__ xsrc, const float* __restrict__ loc,
    float* __restrict__ featg){
  int gid = blockIdx.x*256 + threadIdx.x;
  int t = gid >> 6;
  int b = t >> 14;
  int px = cell_of(loc[2*t],   64.f, 127);
  int py = cell_of(loc[2*t+1], 64.f, 127);
  int cell = (b*GH + py)*GW + px;
  atomicAdd(&featg[cell*NC + (gid & 63)], xsrc[gid]);
}

__global__ __launch_bounds__(256) void k_scatter_aux(
    const float* __restrict__ loc, const float* __restrict__ csrc,
    float* __restrict__ cnt, float* __restrict__ csum, float* __restrict__ ccnt){
  int t = blockIdx.x*256 + threadIdx.x;
  int b = t >> 14;
  int px = cell_of(loc[2*t],   64.f, 127);
  int py = cell_of(loc[2*t+1], 64.f, 127);
  atomicAdd(&cnt[(b*GH+py)*GW+px], 1.0f);
  int qx = cell_of(loc[2*t],   8.f, 15);
  int qy = cell_of(loc[2*t+1], 8.f, 15);
  int cell = b*GM + qy*16 + qx;
  atomicAdd(&csum[cell], csrc[t]);
  atomicAdd(&ccnt[cell], 1.0f);
}

__global__ __launch_bounds__(256) void k_finalize_feat(
    float* __restrict__ featg, const float* __restrict__ cnt){
  int gid = blockIdx.x*256 + threadIdx.x;
  float cn = cnt[gid>>6];
  float v  = featg[gid];
  featg[gid] = (cn > 0.f) ? v/(cn+1e-6f) : 0.f;
}

__global__ __launch_bounds__(256) void k_finalize_conf(
    const float* __restrict__ csum, const float* __restrict__ ccnt,
    float* __restrict__ conf){
  int i = blockIdx.x*256 + threadIdx.x;
  float cn = ccnt[i];
  conf[i] = (cn > 0.f) ? csum[i]/(cn+1e-6f) : 0.f;
}

// 9x9 gaussian hole fill; writes only cnt==0 pixels (taps read only cnt>0).
__global__ __launch_bounds__(256) void k_fill(
    const float* __restrict__ cnt, float* __restrict__ feat){
  int p = blockIdx.x*256 + threadIdx.x;
  if (cnt[p] > 0.f) return;
  int b = p>>14, py=(p>>7)&127, px=p&127;
  const float fn = 0.039788735772973836f;    // 1/(2*pi*var), var=4
  float g1[9];
  #pragma unroll
  for (int i=0;i<9;++i){ float d=(float)i-4.f; g1[i]=__expf(-d*d*0.125f); }
  float4 acc[16];
  #pragma unroll
  for (int i=0;i<16;++i) acc[i]=make_float4(0.f,0.f,0.f,0.f);
  float msum=0.f;
  for (int dy=0; dy<9; ++dy){
    int iy = reflect128(py-4+dy);
    for (int dx=0; dx<9; ++dx){
      int ix = reflect128(px-4+dx);
      int q  = (b*GH+iy)*GW+ix;
      if (cnt[q] <= 0.f) continue;
      float wn = g1[dy]*g1[dx]*fn;
      msum += wn;
      const float4* fr = (const float4*)&feat[q*NC];
      #pragma unroll
      for (int k=0;k<16;++k){
        float4 vv = fr[k];
        acc[k].x += wn*vv.x; acc[k].y += wn*vv.y;
        acc[k].z += wn*vv.z; acc[k].w += wn*vv.w;
      }
    }
  }
  if (msum <= 0.f) return;
  float inv = 1.f/(msum + 1e-6f);
  float4* o = (float4*)&feat[p*NC];
  #pragma unroll
  for (int k=0;k<16;++k)
    o[k] = make_float4(acc[k].x*inv, acc[k].y*inv, acc[k].z*inv, acc[k].w*inv);
}

// stride-8 8x8 conv as split-K GEMM: M=nb*256 patches, K split by kh, N=64
__global__ __launch_bounds__(256) void k_srconv(
    const float* __restrict__ feat, const float* __restrict__ srw,
    float* __restrict__ xs0){
  alignas(16) __shared__ float A[64*65];
  alignas(16) __shared__ float Bs[64*64];
  int mt = blockIdx.x, kh = blockIdx.y;
  int t = threadIdx.x;
  int tm = t>>4, tn = t&15;
  float acc[4][4] = {{0.f}};
  for (int kc=0; kc<8; ++kc){
    __syncthreads();
    for (int idx=t; idx<4096; idx+=256){
      int mr = idx>>6, kk = idx&63;
      int m = mt*64+mr;
      int b = m>>8, oh=(m>>4)&15, ow=m&15;
      A[mr*65+kk] = feat[(((b*GH)+(oh*8+kh))*GW + ow*8)*NC + kc*64 + kk];
    }
    for (int idx=t; idx<4096; idx+=256)
      Bs[idx] = srw[(kh*512 + kc*64)*64 + idx];
    __syncthreads();
    for (int kk=0; kk<64; ++kk){
      float4 bv = *(const float4*)&Bs[kk*64 + tn*4];
      #pragma unroll
      for (int i=0;i<4;++i){
        float av = A[(tm*4+i)*65 + kk];
        acc[i][0] += av*bv.x; acc[i][1] += av*bv.y;
        acc[i][2] += av*bv.z; acc[i][3] += av*bv.w;
      }
    }
  }
  #pragma unroll
  for (int i=0;i<4;++i)
    #pragma unroll
    for (int j=0;j<4;++j)
      atomicAdd(&xs0[(mt*64+tm*4+i)*64 + tn*4+j], acc[i][j]);
}

// layernorm(xs0 + sr_b) -> xs   (wave per row)
__global__ __launch_bounds__(256) void k_ln(
    const float* __restrict__ xs0, const float* __restrict__ srb,
    const float* __restrict__ nw, const float* __restrict__ nbv,
    float* __restrict__ xs){
  int row  = blockIdx.x*4 + (threadIdx.x>>6);
  int lane = threadIdx.x & 63;
  float v = xs0[row*64+lane] + srb[lane];
  float s = v;
  #pragma unroll
  for (int off=32; off; off>>=1) s += __shfl_xor(s, off, 64);
  float mean = s*(1.f/64.f);
  float d = v - mean;
  float s2 = d*d;
  #pragma unroll
  for (int off=32; off; off>>=1) s2 += __shfl_xor(s2, off, 64);
  float var = s2*(1.f/64.f);
  xs[row*64+lane] = d*(1.f/sqrtf(var+1e-5f))*nw[lane] + nbv[lane];
}

// kv: thread per (r,d): raw k and v rows.
__global__ __launch_bounds__(256) void k_kv1(
    const float* __restrict__ xs, const float* __restrict__ kvw,
    float* __restrict__ kraw, float* __restrict__ vraw){
  int gid = blockIdx.x*256 + threadIdx.x;
  int r = gid >> 6, d = gid & 63;
  const float* xr = &xs[r*64];
  float ka=0.f, va=0.f;
  for (int c=0;c<64;++c){
    float xc = xr[c];
    ka += xc*kvw[d*64+c];
    va += xc*kvw[(64+d)*64+c];
  }
  kraw[gid] = ka;                              // [r][d]
  vraw[gid] = va;                              // [r][d]
}

// fold q_w into K (K' = k @ q_w) and proj_w into V (Vp = v @ proj_w^T),
// emitting bf16 buffers PRE-PACKED in MFMA B-fragment order:
//  KB[b][nt][kb][h][l15][j] = K'[16nt+l15][32kb+8h+j]     (QK B-operand)
//  VB[b][ct][kb2][h][n15][j] = Vp[32kb2+8h+j][16ct+n15]   (PV B-operand)
__global__ __launch_bounds__(256) void k_kvproj2(
    const float* __restrict__ kraw, const float* __restrict__ vraw,
    const float* __restrict__ qw, const float* __restrict__ pw,
    ushort* __restrict__ KB, ushort* __restrict__ VB){
  int gid = blockIdx.x*256 + threadIdx.x;
  int r = gid >> 6, c = gid & 63;              // r = b*256+m
  int b = r >> 8, m = r & 255;
  const float* kr = &kraw[r*64];
  const float* vr = &vraw[r*64];
  float ak=0.f, av=0.f;
  for (int i=0;i<64;++i){
    ak += kr[i]*qw[i*64+c];                    // K'[m][c]
    av += vr[i]*pw[c*64+i];                    // Vp[m][c]
  }
  {
    int nt = m>>4, l15 = m&15, kb = c>>5, h = (c>>3)&3, j = c&7;
    KB[((((b*16 + nt)*2 + kb)*4 + h)*16 + l15)*8 + j] = f2bf(ak);
  }
  {
    int ct = c>>4, n15 = c&15, kb2 = m>>5, h2 = (m>>3)&3, j2 = m&7;
    VB[((((b*4 + ct)*8 + kb2)*4 + h2)*16 + n15)*8 + j2] = f2bf(av);
  }
}

// MFMA attention: wave = 16 q-rows. QK (32 mfma) -> softmax in regs ->
// P to wave-private swizzled LDS (A-frag order) -> PV (32 mfma).
__global__ __launch_bounds__(256) void k_attn3(
    const float* __restrict__ x, const ushort* __restrict__ KB,
    const ushort* __restrict__ VB, const float* __restrict__ conf,
    const float* __restrict__ projb, float* __restrict__ out){
  __shared__ ushort P[4*4096];                 // 8KB per wave
  int t = threadIdx.x, w = t>>6, l = t&63;
  int b = blockIdx.x >> 8;
  int row0 = ((blockIdx.x & 255) << 6) + (w<<4);
  int l15 = l & 15, h = l >> 4;
  const ushort* KBb = KB + b*16384;
  const ushort* VBb = VB + b*16384;

  // A-frags from x rows (f32 -> bf16): lane: row=l15, k = 8h + 32kb + j
  bf16x8 xa[2];
  {
    const float* xr = x + (size_t)(b*NN + row0 + l15)*64 + h*8;
    #pragma unroll
    for (int kb=0; kb<2; ++kb){
      float4 a0 = *(const float4*)(xr + 32*kb);
      float4 a1 = *(const float4*)(xr + 32*kb + 4);
      bf16x8 v;
      v[0]=(short)f2bf(a0.x); v[1]=(short)f2bf(a0.y);
      v[2]=(short)f2bf(a0.z); v[3]=(short)f2bf(a0.w);
      v[4]=(short)f2bf(a1.x); v[5]=(short)f2bf(a1.y);
      v[6]=(short)f2bf(a1.z); v[7]=(short)f2bf(a1.w);
      xa[kb]=v;
    }
  }

  // QK: acc[nt] C-tile rows=q (4h+reg), cols=m (16nt+l15)
  f32x4 acc[16];
  #pragma unroll
  for (int nt=0;nt<16;++nt) acc[nt] = (f32x4){0.f,0.f,0.f,0.f};
  #pragma unroll 4
  for (int nt=0;nt<16;++nt){
    bf16x8 b0 = *(const bf16x8*)(KBb + (nt*2+0)*512 + l*8);
    bf16x8 b1 = *(const bf16x8*)(KBb + (nt*2+1)*512 + l*8);
    acc[nt] = __builtin_amdgcn_mfma_f32_16x16x32_bf16(xa[0], b0, acc[nt], 0,0,0);
    acc[nt] = __builtin_amdgcn_mfma_f32_16x16x32_bf16(xa[1], b1, acc[nt], 0,0,0);
  }

  // softmax (no max-subtract: |s*0.125+conf| < ~1.5) ; P -> LDS bf16,
  // A-frag-ordered [kb2][ld][j] with XOR swizzle (idx ^= ld&0x38).
  float rs[4] = {0.f,0.f,0.f,0.f};
  ushort* Pw = P + w*4096;
  #pragma unroll
  for (int nt=0;nt<16;++nt){
    float cf = conf[b*GM + nt*16 + l15];
    #pragma unroll
    for (int reg=0;reg<4;++reg){
      float p = __expf(fmaf(acc[nt][reg], 0.125f, cf));
      rs[reg] += p;
      int m   = nt*16 + l15;
      int row = h*4 + reg;
      int ld  = ((m>>3)&3)*16 + row;
      int idx = ((m>>5)*512 + ld*8 + (m&7)) ^ (ld & 0x38);
      Pw[idx] = f2bf(p);
    }
  }
  #pragma unroll
  for (int off=1; off<16; off<<=1){
    #pragma unroll
    for (int reg=0;reg<4;++reg) rs[reg] += __shfl_xor(rs[reg], off, 64);
  }

  // PV: A = P (swizzled LDS), B = VB; C rows=q (4h+reg), cols=c (16ct+l15)
  f32x4 oacc[4];
  #pragma unroll
  for (int ct=0;ct<4;++ct) oacc[ct] = (f32x4){0.f,0.f,0.f,0.f};
  #pragma unroll 2
  for (int kb2=0;kb2<8;++kb2){
    int ridx = (kb2*512 + l*8) ^ (l & 0x38);
    bf16x8 pa = *(const bf16x8*)(Pw + ridx);
    #pragma unroll
    for (int ct=0;ct<4;++ct){
      bf16x8 vb = *(const bf16x8*)(VBb + (ct*8+kb2)*512 + l*8);
      oacc[ct] = __builtin_amdgcn_mfma_f32_16x16x32_bf16(pa, vb, oacc[ct], 0,0,0);
    }
  }

  #pragma unroll
  for (int ct=0;ct<4;++ct){
    float pb4 = projb[ct*16 + l15];
    #pragma unroll
    for (int reg=0;reg<4;++reg){
      int row = h*4 + reg;
      out[(size_t)(b*NN + row0 + row)*64 + ct*16 + l15] =
          oacc[ct][reg]/rs[reg] + pb4;
    }
  }
}

extern "C" void kernel_launch(void* const* d_in, const int* in_sizes, int n_in,
                              void* d_out, int out_size, void* d_ws, size_t ws_size,
                              hipStream_t stream){
  const float* x    = (const float*)d_in[0];
  const float* xsrc = (const float*)d_in[1];
  const float* loc  = (const float*)d_in[2];
  const float* csrc = (const float*)d_in[3];
  const float* qw   = (const float*)d_in[4];
  const float* kvw  = (const float*)d_in[5];
  const float* srw  = (const float*)d_in[6];
  const float* srb  = (const float*)d_in[7];
  const float* nw   = (const float*)d_in[8];
  const float* nbv  = (const float*)d_in[9];
  const float* pw   = (const float*)d_in[10];
  const float* pb   = (const float*)d_in[11];
  float* out = (float*)d_out;                  // reference output dtype = f32
  float* ws = (float*)d_ws;

  // zeroed: feat,cnt,csum,ccnt,xs0 ; live: conf,xs,kraw,vraw + KB/VB (bf16)
  size_t full_floats = 8ull*(GH*GW*NC + GH*GW + GM + GM + GM*NC)
                     + 8ull*(GM + 3*GM*NC + 16384);
  int nb    = (ws_size >= full_floats*sizeof(float)) ? 8 : 1;
  int iters = 8 / nb;

  size_t SZf = (size_t)nb*GH*GW*NC;
  size_t SZc = (size_t)nb*GH*GW;
  size_t SZs = (size_t)nb*GM;
  size_t SZx = (size_t)nb*GM*NC;
  size_t of_feat = 0;
  size_t of_cnt  = of_feat + SZf;
  size_t of_csum = of_cnt  + SZc;
  size_t of_ccnt = of_csum + SZs;
  size_t of_xs0  = of_ccnt + SZs;
  size_t zero_sz = of_xs0  + SZx;
  size_t of_conf = zero_sz;
  size_t of_xs   = of_conf + SZs;
  size_t of_kr   = of_xs   + SZx;
  size_t of_vr   = of_kr   + SZx;
  size_t of_kb   = of_vr   + SZx;              // nb*16384 ushort = nb*8192 floats
  size_t of_vb   = of_kb   + (size_t)nb*8192;

  for (int it = 0; it < iters; ++it){
    size_t b0 = (size_t)it*nb;
    const float* xsrc_b = xsrc + b0*NN*NC;
    const float* loc_b  = loc  + b0*NN*2;
    const float* csrc_b = csrc + b0*NN;
    const float* x_b    = x    + b0*NN*NC;
    float*       out_b  = out  + b0*NN*NC;

    hipMemsetAsync(ws, 0, zero_sz*sizeof(float), stream);
    k_scatter_feat <<<nb*NN*NC/256, 256, 0, stream>>>(xsrc_b, loc_b, ws+of_feat);
    k_scatter_aux  <<<nb*NN/256,    256, 0, stream>>>(loc_b, csrc_b, ws+of_cnt, ws+of_csum, ws+of_ccnt);
    k_finalize_feat<<<nb*GH*GW*NC/256, 256, 0, stream>>>(ws+of_feat, ws+of_cnt);
    k_finalize_conf<<<(nb*GM+255)/256, 256, 0, stream>>>(ws+of_csum, ws+of_ccnt, ws+of_conf);
    k_fill         <<<nb*GH*GW/256, 256, 0, stream>>>(ws+of_cnt, ws+of_feat);
    dim3 gconv(nb*GM/64, 8);
    k_srconv       <<<gconv,        256, 0, stream>>>(ws+of_feat, srw, ws+of_xs0);
    k_ln           <<<nb*GM/4,      256, 0, stream>>>(ws+of_xs0, srb, nw, nbv, ws+of_xs);
    k_kv1          <<<nb*GM*NC/256, 256, 0, stream>>>(ws+of_xs, kvw, ws+of_kr, ws+of_vr);
    k_kvproj2      <<<nb*GM*NC/256, 256, 0, stream>>>(ws+of_kr, ws+of_vr, qw, pw,
                                                      (ushort*)(ws+of_kb), (ushort*)(ws+of_vb));
    k_attn3        <<<nb*NN/64,     256, 0, stream>>>(x_b, (const ushort*)(ws+of_kb),
                                                      (const ushort*)(ws+of_vb),
                                                      ws+of_conf, pb, out_b);
  }
}

// Round 9
// 347.477 us; speedup vs baseline: 3.2023x; 1.0773x over previous
//
#include <hip/hip_runtime.h>
#include <hip/hip_bf16.h>

#define NN 16384
#define NC 64
#define GH 128
#define GW 128
#define GM 256

typedef __attribute__((ext_vector_type(8))) short bf16x8;
typedef __attribute__((ext_vector_type(4))) float f32x4;

static __device__ __forceinline__ int reflect128(int i){
  if (i < 0) i = -i;
  if (i > 127) i = 254 - i;
  return i;
}

static __device__ __forceinline__ ushort f2bf(float f){
  union { float f; unsigned u; } v; v.f = f;
  unsigned r = v.u + 0x7fffu + ((v.u >> 16) & 1u);   // RNE, no NaN inputs
  return (ushort)(r >> 16);
}

// px = round(0.5*(loc+1)*S - 0.5): (loc+1) rounds once; *S2 (pow2) exact;
// -0.5 rounds once == reference's f32 sequence bit-for-bit.
static __device__ __forceinline__ int cell_of(float l, float S2, int hi){
  l = fminf(fmaxf(l, -1.f), 1.f);
  float u = l + 1.f;
  int p = (int)rintf(u*S2 - 0.5f);
  return min(max(p,0),hi);
}

__global__ __launch_bounds__(256) void k_scatter_feat(
    const float* __restrict__ xsrc, const float* __restrict__ loc,
    float* __restrict__ featg){
  int gid = blockIdx.x*256 + threadIdx.x;
  int t = gid >> 6;
  int b = t >> 14;
  int px = cell_of(loc[2*t],   64.f, 127);
  int py = cell_of(loc[2*t+1], 64.f, 127);
  int cell = (b*GH + py)*GW + px;
  atomicAdd(&featg[cell*NC + (gid & 63)], xsrc[gid]);
}

__global__ __launch_bounds__(256) void k_scatter_aux(
    const float* __restrict__ loc, const float* __restrict__ csrc,
    float* __restrict__ cnt, float* __restrict__ csum, float* __restrict__ ccnt){
  int t = blockIdx.x*256 + threadIdx.x;
  int b = t >> 14;
  int px = cell_of(loc[2*t],   64.f, 127);
  int py = cell_of(loc[2*t+1], 64.f, 127);
  atomicAdd(&cnt[(b*GH+py)*GW+px], 1.0f);
  int qx = cell_of(loc[2*t],   8.f, 15);
  int qy = cell_of(loc[2*t+1], 8.f, 15);
  int cell = b*GM + qy*16 + qx;
  atomicAdd(&csum[cell], csrc[t]);
  atomicAdd(&ccnt[cell], 1.0f);
}

__global__ __launch_bounds__(256) void k_finalize_feat(
    float* __restrict__ featg, const float* __restrict__ cnt){
  int gid = blockIdx.x*256 + threadIdx.x;
  float cn = cnt[gid>>6];
  float v  = featg[gid];
  featg[gid] = (cn > 0.f) ? v/(cn+1e-6f) : 0.f;
}

__global__ __launch_bounds__(256) void k_finalize_conf(
    const float* __restrict__ csum, const float* __restrict__ ccnt,
    float* __restrict__ conf){
  int i = blockIdx.x*256 + threadIdx.x;
  float cn = ccnt[i];
  conf[i] = (cn > 0.f) ? csum[i]/(cn+1e-6f) : 0.f;
}

// 9x9 gaussian hole fill; 4 threads per pixel (16 channels each) -> no spill.
__global__ __launch_bounds__(256) void k_fill2(
    const float* __restrict__ cnt, float* __restrict__ feat){
  int gid = blockIdx.x*256 + threadIdx.x;
  int p = gid >> 2, cg = gid & 3;
  if (cnt[p] > 0.f) return;
  int b = p>>14, py=(p>>7)&127, px=p&127;
  const float fn = 0.039788735772973836f;    // 1/(2*pi*var), var=4
  float g1[9];
  #pragma unroll
  for (int i=0;i<9;++i){ float d=(float)i-4.f; g1[i]=__expf(-d*d*0.125f); }
  float4 acc[4];
  #pragma unroll
  for (int i=0;i<4;++i) acc[i]=make_float4(0.f,0.f,0.f,0.f);
  float msum=0.f;
  for (int dy=0; dy<9; ++dy){
    int iy = reflect128(py-4+dy);
    for (int dx=0; dx<9; ++dx){
      int ix = reflect128(px-4+dx);
      int q  = (b*GH+iy)*GW+ix;
      if (cnt[q] <= 0.f) continue;
      float wn = g1[dy]*g1[dx]*fn;
      msum += wn;
      const float4* fr = (const float4*)&feat[q*NC + cg*16];
      #pragma unroll
      for (int k=0;k<4;++k){
        float4 vv = fr[k];
        acc[k].x += wn*vv.x; acc[k].y += wn*vv.y;
        acc[k].z += wn*vv.z; acc[k].w += wn*vv.w;
      }
    }
  }
  if (msum <= 0.f) return;
  float inv = 1.f/(msum + 1e-6f);
  float4* o = (float4*)&feat[p*NC + cg*16];
  #pragma unroll
  for (int k=0;k<4;++k)
    o[k] = make_float4(acc[k].x*inv, acc[k].y*inv, acc[k].z*inv, acc[k].w*inv);
}

// stride-8 8x8 conv as split-K GEMM: M=nb*256 patches, K split by kh, N=64
__global__ __launch_bounds__(256) void k_srconv(
    const float* __restrict__ feat, const float* __restrict__ srw,
    float* __restrict__ xs0){
  alignas(16) __shared__ float A[64*65];
  alignas(16) __shared__ float Bs[64*64];
  int mt = blockIdx.x, kh = blockIdx.y;
  int t = threadIdx.x;
  int tm = t>>4, tn = t&15;
  float acc[4][4] = {{0.f}};
  for (int kc=0; kc<8; ++kc){
    __syncthreads();
    for (int idx=t; idx<4096; idx+=256){
      int mr = idx>>6, kk = idx&63;
      int m = mt*64+mr;
      int b = m>>8, oh=(m>>4)&15, ow=m&15;
      A[mr*65+kk] = feat[(((b*GH)+(oh*8+kh))*GW + ow*8)*NC + kc*64 + kk];
    }
    for (int idx=t; idx<4096; idx+=256)
      Bs[idx] = srw[(kh*512 + kc*64)*64 + idx];
    __syncthreads();
    for (int kk=0; kk<64; ++kk){
      float4 bv = *(const float4*)&Bs[kk*64 + tn*4];
      #pragma unroll
      for (int i=0;i<4;++i){
        float av = A[(tm*4+i)*65 + kk];
        acc[i][0] += av*bv.x; acc[i][1] += av*bv.y;
        acc[i][2] += av*bv.z; acc[i][3] += av*bv.w;
      }
    }
  }
  #pragma unroll
  for (int i=0;i<4;++i)
    #pragma unroll
    for (int j=0;j<4;++j)
      atomicAdd(&xs0[(mt*64+tm*4+i)*64 + tn*4+j], acc[i][j]);
}

// layernorm(xs0 + sr_b) -> xs   (wave per row)
__global__ __launch_bounds__(256) void k_ln(
    const float* __restrict__ xs0, const float* __restrict__ srb,
    const float* __restrict__ nw, const float* __restrict__ nbv,
    float* __restrict__ xs){
  int row  = blockIdx.x*4 + (threadIdx.x>>6);
  int lane = threadIdx.x & 63;
  float v = xs0[row*64+lane] + srb[lane];
  float s = v;
  #pragma unroll
  for (int off=32; off; off>>=1) s += __shfl_xor(s, off, 64);
  float mean = s*(1.f/64.f);
  float d = v - mean;
  float s2 = d*d;
  #pragma unroll
  for (int off=32; off; off>>=1) s2 += __shfl_xor(s2, off, 64);
  float var = s2*(1.f/64.f);
  xs[row*64+lane] = d*(1.f/sqrtf(var+1e-5f))*nw[lane] + nbv[lane];
}

// kv: thread per (r,d): raw k and v rows.
__global__ __launch_bounds__(256) void k_kv1(
    const float* __restrict__ xs, const float* __restrict__ kvw,
    float* __restrict__ kraw, float* __restrict__ vraw){
  int gid = blockIdx.x*256 + threadIdx.x;
  int r = gid >> 6, d = gid & 63;
  const float* xr = &xs[r*64];
  float ka=0.f, va=0.f;
  for (int c=0;c<64;++c){
    float xc = xr[c];
    ka += xc*kvw[d*64+c];
    va += xc*kvw[(64+d)*64+c];
  }
  kraw[gid] = ka;                              // [r][d]
  vraw[gid] = va;                              // [r][d]
}

// fold q_w into K (K' = k @ q_w) and proj_w into V (Vp = v @ proj_w^T),
// emitting bf16 buffers PRE-PACKED in MFMA B-fragment order:
//  KB[b][nt][kb][h][l15][j] = K'[16nt+l15][32kb+8h+j]     (QK B-operand)
//  VB[b][ct][kb2][h][n15][j] = Vp[32kb2+8h+j][16ct+n15]   (PV B-operand)
__global__ __launch_bounds__(256) void k_kvproj2(
    const float* __restrict__ kraw, const float* __restrict__ vraw,
    const float* __restrict__ qw, const float* __restrict__ pw,
    ushort* __restrict__ KB, ushort* __restrict__ VB){
  int gid = blockIdx.x*256 + threadIdx.x;
  int r = gid >> 6, c = gid & 63;              // r = b*256+m
  int b = r >> 8, m = r & 255;
  const float* kr = &kraw[r*64];
  const float* vr = &vraw[r*64];
  float ak=0.f, av=0.f;
  for (int i=0;i<64;++i){
    ak += kr[i]*qw[i*64+c];                    // K'[m][c]
    av += vr[i]*pw[c*64+i];                    // Vp[m][c]
  }
  {
    int nt = m>>4, l15 = m&15, kb = c>>5, h = (c>>3)&3, j = c&7;
    KB[((((b*16 + nt)*2 + kb)*4 + h)*16 + l15)*8 + j] = f2bf(ak);
  }
  {
    int ct = c>>4, n15 = c&15, kb2 = m>>5, h2 = (m>>3)&3, j2 = m&7;
    VB[((((b*4 + ct)*8 + kb2)*4 + h2)*16 + n15)*8 + j2] = f2bf(av);
  }
}

// MFMA attention: wave = 16 q-rows. QK (32 mfma) -> softmax in regs ->
// P to wave-private swizzled LDS (A-frag order) -> PV (32 mfma) ->
// out via LDS transpose -> fully-coalesced 256B row writes.
__global__ __launch_bounds__(256) void k_attn4(
    const float* __restrict__ x, const ushort* __restrict__ KB,
    const ushort* __restrict__ VB, const float* __restrict__ conf,
    const float* __restrict__ projb, float* __restrict__ out){
  alignas(16) __shared__ ushort P[4*4096];     // 8KB per wave
  int t = threadIdx.x, w = t>>6, l = t&63;
  int b = blockIdx.x >> 8;
  int row0 = ((blockIdx.x & 255) << 6) + (w<<4);
  int l15 = l & 15, h = l >> 4;
  const ushort* KBb = KB + b*16384;
  const ushort* VBb = VB + b*16384;

  // A-frags from x rows (f32 -> bf16): lane: row=l15, k = 8h + 32kb + j
  bf16x8 xa[2];
  {
    const float* xr = x + (size_t)(b*NN + row0 + l15)*64 + h*8;
    #pragma unroll
    for (int kb=0; kb<2; ++kb){
      float4 a0 = *(const float4*)(xr + 32*kb);
      float4 a1 = *(const float4*)(xr + 32*kb + 4);
      bf16x8 v;
      v[0]=(short)f2bf(a0.x); v[1]=(short)f2bf(a0.y);
      v[2]=(short)f2bf(a0.z); v[3]=(short)f2bf(a0.w);
      v[4]=(short)f2bf(a1.x); v[5]=(short)f2bf(a1.y);
      v[6]=(short)f2bf(a1.z); v[7]=(short)f2bf(a1.w);
      xa[kb]=v;
    }
  }

  // QK: acc[nt] C-tile rows=q (4h+reg), cols=m (16nt+l15)
  f32x4 acc[16];
  #pragma unroll
  for (int nt=0;nt<16;++nt) acc[nt] = (f32x4){0.f,0.f,0.f,0.f};
  #pragma unroll 4
  for (int nt=0;nt<16;++nt){
    bf16x8 b0 = *(const bf16x8*)(KBb + (nt*2+0)*512 + l*8);
    bf16x8 b1 = *(const bf16x8*)(KBb + (nt*2+1)*512 + l*8);
    acc[nt] = __builtin_amdgcn_mfma_f32_16x16x32_bf16(xa[0], b0, acc[nt], 0,0,0);
    acc[nt] = __builtin_amdgcn_mfma_f32_16x16x32_bf16(xa[1], b1, acc[nt], 0,0,0);
  }

  // softmax (no max-subtract: |s*0.125+conf| < ~1.5) ; P -> LDS bf16,
  // A-frag-ordered [kb2][ld][j] with XOR swizzle (idx ^= ld&0x38).
  float rs[4] = {0.f,0.f,0.f,0.f};
  ushort* Pw = P + w*4096;
  #pragma unroll
  for (int nt=0;nt<16;++nt){
    float cf = conf[b*GM + nt*16 + l15];
    #pragma unroll
    for (int reg=0;reg<4;++reg){
      float p = __expf(fmaf(acc[nt][reg], 0.125f, cf));
      rs[reg] += p;
      int m   = nt*16 + l15;
      int row = h*4 + reg;
      int ld  = ((m>>3)&3)*16 + row;
      int idx = ((m>>5)*512 + ld*8 + (m&7)) ^ (ld & 0x38);
      Pw[idx] = f2bf(p);
    }
  }
  #pragma unroll
  for (int off=1; off<16; off<<=1){
    #pragma unroll
    for (int reg=0;reg<4;++reg) rs[reg] += __shfl_xor(rs[reg], off, 64);
  }

  // PV: A = P (swizzled LDS), B = VB; C rows=q (4h+reg), cols=c (16ct+l15)
  f32x4 oacc[4];
  #pragma unroll
  for (int ct=0;ct<4;++ct) oacc[ct] = (f32x4){0.f,0.f,0.f,0.f};
  #pragma unroll 2
  for (int kb2=0;kb2<8;++kb2){
    int ridx = (kb2*512 + l*8) ^ (l & 0x38);
    bf16x8 pa = *(const bf16x8*)(Pw + ridx);
    #pragma unroll
    for (int ct=0;ct<4;++ct){
      bf16x8 vb = *(const bf16x8*)(VBb + (ct*8+kb2)*512 + l*8);
      oacc[ct] = __builtin_amdgcn_mfma_f32_16x16x32_bf16(pa, vb, oacc[ct], 0,0,0);
    }
  }

  // out: register -> LDS transpose (reuse dead P buffer) -> coalesced rows.
  // OT[16][68] f32, wave-private; data-dep on oacc orders it after PV reads.
  float* OT = (float*)Pw;
  #pragma unroll
  for (int ct=0;ct<4;++ct){
    float pb4 = projb[ct*16 + l15];
    #pragma unroll
    for (int reg=0;reg<4;++reg)
      OT[(h*4+reg)*68 + ct*16 + l15] = oacc[ct][reg]/rs[reg] + pb4;
  }
  #pragma unroll
  for (int i=0;i<4;++i){
    int row = i*4 + h;
    float4 v = *(const float4*)&OT[row*68 + l15*4];
    *(float4*)&out[(size_t)(b*NN + row0 + row)*64 + l15*4] = v;
  }
}

extern "C" void kernel_launch(void* const* d_in, const int* in_sizes, int n_in,
                              void* d_out, int out_size, void* d_ws, size_t ws_size,
                              hipStream_t stream){
  const float* x    = (const float*)d_in[0];
  const float* xsrc = (const float*)d_in[1];
  const float* loc  = (const float*)d_in[2];
  const float* csrc = (const float*)d_in[3];
  const float* qw   = (const float*)d_in[4];
  const float* kvw  = (const float*)d_in[5];
  const float* srw  = (const float*)d_in[6];
  const float* srb  = (const float*)d_in[7];
  const float* nw   = (const float*)d_in[8];
  const float* nbv  = (const float*)d_in[9];
  const float* pw   = (const float*)d_in[10];
  const float* pb   = (const float*)d_in[11];
  float* out = (float*)d_out;                  // reference output dtype = f32
  float* ws = (float*)d_ws;

  // zeroed: feat,cnt,csum,ccnt,xs0 ; live: conf,xs,kraw,vraw + KB/VB (bf16)
  size_t full_floats = 8ull*(GH*GW*NC + GH*GW + GM + GM + GM*NC)
                     + 8ull*(GM + 3*GM*NC + 16384);
  int nb    = (ws_size >= full_floats*sizeof(float)) ? 8 : 1;
  int iters = 8 / nb;

  size_t SZf = (size_t)nb*GH*GW*NC;
  size_t SZc = (size_t)nb*GH*GW;
  size_t SZs = (size_t)nb*GM;
  size_t SZx = (size_t)nb*GM*NC;
  size_t of_feat = 0;
  size_t of_cnt  = of_feat + SZf;
  size_t of_csum = of_cnt  + SZc;
  size_t of_ccnt = of_csum + SZs;
  size_t of_xs0  = of_ccnt + SZs;
  size_t zero_sz = of_xs0  + SZx;
  size_t of_conf = zero_sz;
  size_t of_xs   = of_conf + SZs;
  size_t of_kr   = of_xs   + SZx;
  size_t of_vr   = of_kr   + SZx;
  size_t of_kb   = of_vr   + SZx;              // nb*16384 ushort = nb*8192 floats
  size_t of_vb   = of_kb   + (size_t)nb*8192;

  for (int it = 0; it < iters; ++it){
    size_t b0 = (size_t)it*nb;
    const float* xsrc_b = xsrc + b0*NN*NC;
    const float* loc_b  = loc  + b0*NN*2;
    const float* csrc_b = csrc + b0*NN;
    const float* x_b    = x    + b0*NN*NC;
    float*       out_b  = out  + b0*NN*NC;

    hipMemsetAsync(ws, 0, zero_sz*sizeof(float), stream);
    k_scatter_feat <<<nb*NN*NC/256, 256, 0, stream>>>(xsrc_b, loc_b, ws+of_feat);
    k_scatter_aux  <<<nb*NN/256,    256, 0, stream>>>(loc_b, csrc_b, ws+of_cnt, ws+of_csum, ws+of_ccnt);
    k_finalize_feat<<<nb*GH*GW*NC/256, 256, 0, stream>>>(ws+of_feat, ws+of_cnt);
    k_finalize_conf<<<(nb*GM+255)/256, 256, 0, stream>>>(ws+of_csum, ws+of_ccnt, ws+of_conf);
    k_fill2        <<<nb*GH*GW*4/256, 256, 0, stream>>>(ws+of_cnt, ws+of_feat);
    dim3 gconv(nb*GM/64, 8);
    k_srconv       <<<gconv,        256, 0, stream>>>(ws+of_feat, srw, ws+of_xs0);
    k_ln           <<<nb*GM/4,      256, 0, stream>>>(ws+of_xs0, srb, nw, nbv, ws+of_xs);
    k_kv1          <<<nb*GM*NC/256, 256, 0, stream>>>(ws+of_xs, kvw, ws+of_kr, ws+of_vr);
    k_kvproj2      <<<nb*GM*NC/256, 256, 0, stream>>>(ws+of_kr, ws+of_vr, qw, pw,
                                                      (ushort*)(ws+of_kb), (ushort*)(ws+of_vb));
    k_attn4        <<<nb*NN/64,     256, 0, stream>>>(x_b, (const ushort*)(ws+of_kb),
                                                      (const ushort*)(ws+of_vb),
                                                      ws+of_conf, pb, out_b);
  }
}

// Round 10
// 307.675 us; speedup vs baseline: 3.6166x; 1.1294x over previous
//
#include <hip/hip_runtime.h>
#include <hip/hip_bf16.h>

#define NN 16384
#define NC 64
#define GH 128
#define GW 128
#define GM 256

typedef __attribute__((ext_vector_type(8))) short bf16x8;
typedef __attribute__((ext_vector_type(4))) float f32x4;

static __device__ __forceinline__ int reflect128(int i){
  if (i < 0) i = -i;
  if (i > 127) i = 254 - i;
  return i;
}

static __device__ __forceinline__ ushort f2bf(float f){
  union { float f; unsigned u; } v; v.f = f;
  unsigned r = v.u + 0x7fffu + ((v.u >> 16) & 1u);   // RNE, no NaN inputs
  return (ushort)(r >> 16);
}

// px = round(0.5*(loc+1)*S - 0.5): (loc+1) rounds once; *S2 (pow2) exact;
// -0.5 rounds once == reference's f32 sequence bit-for-bit.
static __device__ __forceinline__ int cell_of(float l, float S2, int hi){
  l = fminf(fmaxf(l, -1.f), 1.f);
  float u = l + 1.f;
  int p = (int)rintf(u*S2 - 0.5f);
  return min(max(p,0),hi);
}

__global__ __launch_bounds__(256) void k_scatter_feat(
    const float* __restrict__ xsrc, const float* __restrict__ loc,
    float* __restrict__ featg){
  int gid = blockIdx.x*256 + threadIdx.x;
  int t = gid >> 6;
  int b = t >> 14;
  int px = cell_of(loc[2*t],   64.f, 127);
  int py = cell_of(loc[2*t+1], 64.f, 127);
  int cell = (b*GH + py)*GW + px;
  atomicAdd(&featg[cell*NC + (gid & 63)], xsrc[gid]);
}

__global__ __launch_bounds__(256) void k_scatter_aux(
    const float* __restrict__ loc, const float* __restrict__ csrc,
    float* __restrict__ cnt, float* __restrict__ csum, float* __restrict__ ccnt){
  int t = blockIdx.x*256 + threadIdx.x;
  int b = t >> 14;
  int px = cell_of(loc[2*t],   64.f, 127);
  int py = cell_of(loc[2*t+1], 64.f, 127);
  atomicAdd(&cnt[(b*GH+py)*GW+px], 1.0f);
  int qx = cell_of(loc[2*t],   8.f, 15);
  int qy = cell_of(loc[2*t+1], 8.f, 15);
  int cell = b*GM + qy*16 + qx;
  atomicAdd(&csum[cell], csrc[t]);
  atomicAdd(&ccnt[cell], 1.0f);
}

__global__ __launch_bounds__(256) void k_finalize_feat(
    float* __restrict__ featg, const float* __restrict__ cnt){
  int gid = blockIdx.x*256 + threadIdx.x;
  float cn = cnt[gid>>6];
  float v  = featg[gid];
  featg[gid] = (cn > 0.f) ? v/(cn+1e-6f) : 0.f;
}

__global__ __launch_bounds__(256) void k_finalize_conf(
    const float* __restrict__ csum, const float* __restrict__ ccnt,
    float* __restrict__ conf){
  int i = blockIdx.x*256 + threadIdx.x;
  float cn = ccnt[i];
  conf[i] = (cn > 0.f) ? csum[i]/(cn+1e-6f) : 0.f;
}

// 9x9 gaussian hole fill; 4 threads per pixel (16 channels each) -> no spill.
__global__ __launch_bounds__(256) void k_fill2(
    const float* __restrict__ cnt, float* __restrict__ feat){
  int gid = blockIdx.x*256 + threadIdx.x;
  int p = gid >> 2, cg = gid & 3;
  if (cnt[p] > 0.f) return;
  int b = p>>14, py=(p>>7)&127, px=p&127;
  const float fn = 0.039788735772973836f;    // 1/(2*pi*var), var=4
  float g1[9];
  #pragma unroll
  for (int i=0;i<9;++i){ float d=(float)i-4.f; g1[i]=__expf(-d*d*0.125f); }
  float4 acc[4];
  #pragma unroll
  for (int i=0;i<4;++i) acc[i]=make_float4(0.f,0.f,0.f,0.f);
  float msum=0.f;
  for (int dy=0; dy<9; ++dy){
    int iy = reflect128(py-4+dy);
    for (int dx=0; dx<9; ++dx){
      int ix = reflect128(px-4+dx);
      int q  = (b*GH+iy)*GW+ix;
      if (cnt[q] <= 0.f) continue;
      float wn = g1[dy]*g1[dx]*fn;
      msum += wn;
      const float4* fr = (const float4*)&feat[q*NC + cg*16];
      #pragma unroll
      for (int k=0;k<4;++k){
        float4 vv = fr[k];
        acc[k].x += wn*vv.x; acc[k].y += wn*vv.y;
        acc[k].z += wn*vv.z; acc[k].w += wn*vv.w;
      }
    }
  }
  if (msum <= 0.f) return;
  float inv = 1.f/(msum + 1e-6f);
  float4* o = (float4*)&feat[p*NC + cg*16];
  #pragma unroll
  for (int k=0;k<4;++k)
    o[k] = make_float4(acc[k].x*inv, acc[k].y*inv, acc[k].z*inv, acc[k].w*inv);
}

// stride-8 8x8 conv as split-K GEMM: M=nb*256 patches, K split by kh, N=64
__global__ __launch_bounds__(256) void k_srconv(
    const float* __restrict__ feat, const float* __restrict__ srw,
    float* __restrict__ xs0){
  alignas(16) __shared__ float A[64*65];
  alignas(16) __shared__ float Bs[64*64];
  int mt = blockIdx.x, kh = blockIdx.y;
  int t = threadIdx.x;
  int tm = t>>4, tn = t&15;
  float acc[4][4] = {{0.f}};
  for (int kc=0; kc<8; ++kc){
    __syncthreads();
    for (int idx=t; idx<4096; idx+=256){
      int mr = idx>>6, kk = idx&63;
      int m = mt*64+mr;
      int b = m>>8, oh=(m>>4)&15, ow=m&15;
      A[mr*65+kk] = feat[(((b*GH)+(oh*8+kh))*GW + ow*8)*NC + kc*64 + kk];
    }
    for (int idx=t; idx<4096; idx+=256)
      Bs[idx] = srw[(kh*512 + kc*64)*64 + idx];
    __syncthreads();
    for (int kk=0; kk<64; ++kk){
      float4 bv = *(const float4*)&Bs[kk*64 + tn*4];
      #pragma unroll
      for (int i=0;i<4;++i){
        float av = A[(tm*4+i)*65 + kk];
        acc[i][0] += av*bv.x; acc[i][1] += av*bv.y;
        acc[i][2] += av*bv.z; acc[i][3] += av*bv.w;
      }
    }
  }
  #pragma unroll
  for (int i=0;i<4;++i)
    #pragma unroll
    for (int j=0;j<4;++j)
      atomicAdd(&xs0[(mt*64+tm*4+i)*64 + tn*4+j], acc[i][j]);
}

// layernorm(xs0 + sr_b) -> xs   (wave per row)
__global__ __launch_bounds__(256) void k_ln(
    const float* __restrict__ xs0, const float* __restrict__ srb,
    const float* __restrict__ nw, const float* __restrict__ nbv,
    float* __restrict__ xs){
  int row  = blockIdx.x*4 + (threadIdx.x>>6);
  int lane = threadIdx.x & 63;
  float v = xs0[row*64+lane] + srb[lane];
  float s = v;
  #pragma unroll
  for (int off=32; off; off>>=1) s += __shfl_xor(s, off, 64);
  float mean = s*(1.f/64.f);
  float d = v - mean;
  float s2 = d*d;
  #pragma unroll
  for (int off=32; off; off>>=1) s2 += __shfl_xor(s2, off, 64);
  float var = s2*(1.f/64.f);
  xs[row*64+lane] = d*(1.f/sqrtf(var+1e-5f))*nw[lane] + nbv[lane];
}

// kv: thread per (r,d): raw k and v rows.
__global__ __launch_bounds__(256) void k_kv1(
    const float* __restrict__ xs, const float* __restrict__ kvw,
    float* __restrict__ kraw, float* __restrict__ vraw){
  int gid = blockIdx.x*256 + threadIdx.x;
  int r = gid >> 6, d = gid & 63;
  const float* xr = &xs[r*64];
  float ka=0.f, va=0.f;
  for (int c=0;c<64;++c){
    float xc = xr[c];
    ka += xc*kvw[d*64+c];
    va += xc*kvw[(64+d)*64+c];
  }
  kraw[gid] = ka;                              // [r][d]
  vraw[gid] = va;                              // [r][d]
}

// fold q_w into K (K' = k @ q_w) and proj_w into V (Vp = v @ proj_w^T),
// emitting bf16 buffers PRE-PACKED in MFMA B-fragment order:
//  KB[b][nt][kb][h][l15][j] = K'[16nt+l15][32kb+8h+j]     (QK B-operand)
//  VB[b][ct][kb2][h][n15][j] = Vp[32kb2+8h+j][16ct+n15]   (PV B-operand)
__global__ __launch_bounds__(256) void k_kvproj2(
    const float* __restrict__ kraw, const float* __restrict__ vraw,
    const float* __restrict__ qw, const float* __restrict__ pw,
    ushort* __restrict__ KB, ushort* __restrict__ VB){
  int gid = blockIdx.x*256 + threadIdx.x;
  int r = gid >> 6, c = gid & 63;              // r = b*256+m
  int b = r >> 8, m = r & 255;
  const float* kr = &kraw[r*64];
  const float* vr = &vraw[r*64];
  float ak=0.f, av=0.f;
  for (int i=0;i<64;++i){
    ak += kr[i]*qw[i*64+c];                    // K'[m][c]
    av += vr[i]*pw[c*64+i];                    // Vp[m][c]
  }
  {
    int nt = m>>4, l15 = m&15, kb = c>>5, h = (c>>3)&3, j = c&7;
    KB[((((b*16 + nt)*2 + kb)*4 + h)*16 + l15)*8 + j] = f2bf(ak);
  }
  {
    int ct = c>>4, n15 = c&15, kb2 = m>>5, h2 = (m>>3)&3, j2 = m&7;
    VB[((((b*4 + ct)*8 + kb2)*4 + h2)*16 + n15)*8 + j2] = f2bf(av);
  }
}

// MFMA attention: wave = 16 q-rows. QK (32 mfma) -> softmax in regs ->
// P to wave-private swizzled LDS (A-frag order) -> PV (32 mfma) ->
// out via LDS transpose -> fully-coalesced 256B row writes.
// NOTE: all accumulator loops FULLY unrolled (rule #20: partial unroll left
// acc[nt] runtime-indexed -> scratch spill -> 258MB of HBM scratch traffic).
__global__ __launch_bounds__(256) void k_attn5(
    const float* __restrict__ x, const ushort* __restrict__ KB,
    const ushort* __restrict__ VB, const float* __restrict__ conf,
    const float* __restrict__ projb, float* __restrict__ out){
  alignas(16) __shared__ ushort P[4*4096];     // 8KB per wave
  int t = threadIdx.x, w = t>>6, l = t&63;
  int b = blockIdx.x >> 8;
  int row0 = ((blockIdx.x & 255) << 6) + (w<<4);
  int l15 = l & 15, h = l >> 4;
  const ushort* KBb = KB + b*16384;
  const ushort* VBb = VB + b*16384;

  // A-frags from x rows (f32 -> bf16): lane: row=l15, k = 8h + 32kb + j
  bf16x8 xa[2];
  {
    const float* xr = x + (size_t)(b*NN + row0 + l15)*64 + h*8;
    #pragma unroll
    for (int kb=0; kb<2; ++kb){
      float4 a0 = *(const float4*)(xr + 32*kb);
      float4 a1 = *(const float4*)(xr + 32*kb + 4);
      bf16x8 v;
      v[0]=(short)f2bf(a0.x); v[1]=(short)f2bf(a0.y);
      v[2]=(short)f2bf(a0.z); v[3]=(short)f2bf(a0.w);
      v[4]=(short)f2bf(a1.x); v[5]=(short)f2bf(a1.y);
      v[6]=(short)f2bf(a1.z); v[7]=(short)f2bf(a1.w);
      xa[kb]=v;
    }
  }

  // QK: acc[nt] C-tile rows=q (4h+reg), cols=m (16nt+l15)  [FULL unroll]
  f32x4 acc[16];
  #pragma unroll
  for (int nt=0;nt<16;++nt) acc[nt] = (f32x4){0.f,0.f,0.f,0.f};
  #pragma unroll
  for (int nt=0;nt<16;++nt){
    bf16x8 b0 = *(const bf16x8*)(KBb + (nt*2+0)*512 + l*8);
    bf16x8 b1 = *(const bf16x8*)(KBb + (nt*2+1)*512 + l*8);
    acc[nt] = __builtin_amdgcn_mfma_f32_16x16x32_bf16(xa[0], b0, acc[nt], 0,0,0);
    acc[nt] = __builtin_amdgcn_mfma_f32_16x16x32_bf16(xa[1], b1, acc[nt], 0,0,0);
  }

  // softmax (no max-subtract: |s*0.125+conf| < ~1.5) ; P -> LDS bf16,
  // A-frag-ordered [kb2][ld][j] with XOR swizzle (idx ^= ld&0x38).
  float rs[4] = {0.f,0.f,0.f,0.f};
  ushort* Pw = P + w*4096;
  #pragma unroll
  for (int nt=0;nt<16;++nt){
    float cf = conf[b*GM + nt*16 + l15];
    #pragma unroll
    for (int reg=0;reg<4;++reg){
      float p = __expf(fmaf(acc[nt][reg], 0.125f, cf));
      rs[reg] += p;
      int m   = nt*16 + l15;
      int row = h*4 + reg;
      int ld  = ((m>>3)&3)*16 + row;
      int idx = ((m>>5)*512 + ld*8 + (m&7)) ^ (ld & 0x38);
      Pw[idx] = f2bf(p);
    }
  }
  #pragma unroll
  for (int off=1; off<16; off<<=1){
    #pragma unroll
    for (int reg=0;reg<4;++reg) rs[reg] += __shfl_xor(rs[reg], off, 64);
  }

  // PV: A = P (swizzled LDS), B = VB; C rows=q (4h+reg), cols=c (16ct+l15)
  f32x4 oacc[4];
  #pragma unroll
  for (int ct=0;ct<4;++ct) oacc[ct] = (f32x4){0.f,0.f,0.f,0.f};
  #pragma unroll
  for (int kb2=0;kb2<8;++kb2){
    int ridx = (kb2*512 + l*8) ^ (l & 0x38);
    bf16x8 pa = *(const bf16x8*)(Pw + ridx);
    #pragma unroll
    for (int ct=0;ct<4;++ct){
      bf16x8 vb = *(const bf16x8*)(VBb + (ct*8+kb2)*512 + l*8);
      oacc[ct] = __builtin_amdgcn_mfma_f32_16x16x32_bf16(pa, vb, oacc[ct], 0,0,0);
    }
  }

  // out: register -> LDS transpose (reuse dead P buffer) -> coalesced rows.
  float* OT = (float*)Pw;
  #pragma unroll
  for (int ct=0;ct<4;++ct){
    float pb4 = projb[ct*16 + l15];
    #pragma unroll
    for (int reg=0;reg<4;++reg)
      OT[(h*4+reg)*68 + ct*16 + l15] = oacc[ct][reg]/rs[reg] + pb4;
  }
  #pragma unroll
  for (int i=0;i<4;++i){
    int row = i*4 + h;
    float4 v = *(const float4*)&OT[row*68 + l15*4];
    *(float4*)&out[(size_t)(b*NN + row0 + row)*64 + l15*4] = v;
  }
}

extern "C" void kernel_launch(void* const* d_in, const int* in_sizes, int n_in,
                              void* d_out, int out_size, void* d_ws, size_t ws_size,
                              hipStream_t stream){
  const float* x    = (const float*)d_in[0];
  const float* xsrc = (const float*)d_in[1];
  const float* loc  = (const float*)d_in[2];
  const float* csrc = (const float*)d_in[3];
  const float* qw   = (const float*)d_in[4];
  const float* kvw  = (const float*)d_in[5];
  const float* srw  = (const float*)d_in[6];
  const float* srb  = (const float*)d_in[7];
  const float* nw   = (const float*)d_in[8];
  const float* nbv  = (const float*)d_in[9];
  const float* pw   = (const float*)d_in[10];
  const float* pb   = (const float*)d_in[11];
  float* out = (float*)d_out;                  // reference output dtype = f32
  float* ws = (float*)d_ws;

  // zeroed: feat,cnt,csum,ccnt,xs0 ; live: conf,xs,kraw,vraw + KB/VB (bf16)
  size_t full_floats = 8ull*(GH*GW*NC + GH*GW + GM + GM + GM*NC)
                     + 8ull*(GM + 3*GM*NC + 16384);
  int nb    = (ws_size >= full_floats*sizeof(float)) ? 8 : 1;
  int iters = 8 / nb;

  size_t SZf = (size_t)nb*GH*GW*NC;
  size_t SZc = (size_t)nb*GH*GW;
  size_t SZs = (size_t)nb*GM;
  size_t SZx = (size_t)nb*GM*NC;
  size_t of_feat = 0;
  size_t of_cnt  = of_feat + SZf;
  size_t of_csum = of_cnt  + SZc;
  size_t of_ccnt = of_csum + SZs;
  size_t of_xs0  = of_ccnt + SZs;
  size_t zero_sz = of_xs0  + SZx;
  size_t of_conf = zero_sz;
  size_t of_xs   = of_conf + SZs;
  size_t of_kr   = of_xs   + SZx;
  size_t of_vr   = of_kr   + SZx;
  size_t of_kb   = of_vr   + SZx;              // nb*16384 ushort = nb*8192 floats
  size_t of_vb   = of_kb   + (size_t)nb*8192;

  for (int it = 0; it < iters; ++it){
    size_t b0 = (size_t)it*nb;
    const float* xsrc_b = xsrc + b0*NN*NC;
    const float* loc_b  = loc  + b0*NN*2;
    const float* csrc_b = csrc + b0*NN;
    const float* x_b    = x    + b0*NN*NC;
    float*       out_b  = out  + b0*NN*NC;

    hipMemsetAsync(ws, 0, zero_sz*sizeof(float), stream);
    k_scatter_feat <<<nb*NN*NC/256, 256, 0, stream>>>(xsrc_b, loc_b, ws+of_feat);
    k_scatter_aux  <<<nb*NN/256,    256, 0, stream>>>(loc_b, csrc_b, ws+of_cnt, ws+of_csum, ws+of_ccnt);
    k_finalize_feat<<<nb*GH*GW*NC/256, 256, 0, stream>>>(ws+of_feat, ws+of_cnt);
    k_finalize_conf<<<(nb*GM+255)/256, 256, 0, stream>>>(ws+of_csum, ws+of_ccnt, ws+of_conf);
    k_fill2        <<<nb*GH*GW*4/256, 256, 0, stream>>>(ws+of_cnt, ws+of_feat);
    dim3 gconv(nb*GM/64, 8);
    k_srconv       <<<gconv,        256, 0, stream>>>(ws+of_feat, srw, ws+of_xs0);
    k_ln           <<<nb*GM/4,      256, 0, stream>>>(ws+of_xs0, srb, nw, nbv, ws+of_xs);
    k_kv1          <<<nb*GM*NC/256, 256, 0, stream>>>(ws+of_xs, kvw, ws+of_kr, ws+of_vr);
    k_kvproj2      <<<nb*GM*NC/256, 256, 0, stream>>>(ws+of_kr, ws+of_vr, qw, pw,
                                                      (ushort*)(ws+of_kb), (ushort*)(ws+of_vb));
    k_attn5        <<<nb*NN/64,     256, 0, stream>>>(x_b, (const ushort*)(ws+of_kb),
                                                      (const ushort*)(ws+of_vb),
                                                      ws+of_conf, pb, out_b);
  }
}